// Round 1
// baseline (2040.752 us; speedup 1.0000x reference)
//
#include <hip/hip_runtime.h>
#include <hip/hip_bf16.h>
#include <math.h>

// Problem constants
#define S_ 64
#define R_ 256
#define E_ 256
#define P_ 128
#define H_ 8
#define C_ 32
#define NB_ 2
#define SGL_ 384
#define HC_ 256                 // H_*C_
#define SRE (S_ * R_ * E_)      // 4194304

static constexpr float QSCALE = 0.17677669529663687f;  // 1/sqrt(C_)

// ---------------------------------------------------------------- reductions
__device__ __forceinline__ float wave_sum(float x) {
#pragma unroll
  for (int off = 32; off >= 1; off >>= 1) x += __shfl_xor(x, off);
  return x;
}
__device__ __forceinline__ float wave_max(float x) {
#pragma unroll
  for (int off = 32; off >= 1; off >>= 1) x = fmaxf(x, __shfl_xor(x, off));
  return x;
}

// ---------------------------------------------------------------- LayerNorm over 256 features
// one block (256 threads) per row
__global__ __launch_bounds__(256) void ln256_kernel(
    const float* __restrict__ x, const float* __restrict__ sc,
    const float* __restrict__ bi, float* __restrict__ out) {
  int row = blockIdx.x;
  int t = threadIdx.x;
  size_t base = (size_t)row * 256 + t;
  float v = x[base];
  __shared__ float red[4];
  float s1 = wave_sum(v);
  if ((t & 63) == 0) red[t >> 6] = s1;
  __syncthreads();
  float mu = (red[0] + red[1] + red[2] + red[3]) * (1.0f / 256.0f);
  float d = v - mu;
  __syncthreads();
  float s2 = wave_sum(d * d);
  if ((t & 63) == 0) red[t >> 6] = s2;
  __syncthreads();
  float var = (red[0] + red[1] + red[2] + red[3]) * (1.0f / 256.0f);
  out[base] = sc[t] * d * rsqrtf(var + 1e-5f) + bi[t];
}

// ---------------------------------------------------------------- pair bias
// bias[h,qr,kr] = sum_e LN(pair[qr,kr,:])[e] * Wb[e,h]
// one block (128 threads) per (qr*R_+kr)
__global__ __launch_bounds__(128) void pair_bias_kernel(
    const float* __restrict__ pair, const float* __restrict__ sc,
    const float* __restrict__ bi, const float* __restrict__ Wb,
    float* __restrict__ bias_out) {
  int qk = blockIdx.x;
  int t = threadIdx.x;  // 0..127 == P index
  float v = pair[(size_t)qk * P_ + t];
  __shared__ float red[2];
  float s1 = wave_sum(v);
  if ((t & 63) == 0) red[t >> 6] = s1;
  __syncthreads();
  float mu = (red[0] + red[1]) * (1.0f / 128.0f);
  float d = v - mu;
  __syncthreads();
  float s2 = wave_sum(d * d);
  if ((t & 63) == 0) red[t >> 6] = s2;
  __syncthreads();
  float var = (red[0] + red[1]) * (1.0f / 128.0f);
  float z = sc[t] * d * rsqrtf(var + 1e-5f) + bi[t];

  __shared__ float hred[2][H_];
  const float* wp = Wb + (size_t)t * H_;
#pragma unroll
  for (int h = 0; h < H_; ++h) {
    float r = wave_sum(z * wp[h]);
    if ((t & 63) == 0) hred[t >> 6][h] = r;
  }
  __syncthreads();
  if (t < H_) bias_out[(size_t)t * (R_ * R_) + qk] = hred[0][t] + hred[1][t];
}

// ---------------------------------------------------------------- generic fp32 GEMM
// C = act(scale * (A .* A2) @ B + bias) + res ; tiles 64x64, BK=16, 4x4/thread
__global__ __launch_bounds__(256) void gemm_kernel(
    const float* __restrict__ A, const float* __restrict__ A2,
    const float* __restrict__ B, const float* __restrict__ bias,
    const float* __restrict__ res, float* __restrict__ Cmat,
    int M, int N, int K, float scale, int do_sig) {
  __shared__ float As[16][68];  // [k][m], +4 pad: aligned float4 reads, low bank conflict
  __shared__ float Bs[16][64];  // [k][n]
  int tid = threadIdx.x;
  int bm = blockIdx.y * 64, bn = blockIdx.x * 64;
  int tr = (tid >> 4) << 2;  // output row in tile
  int tc = (tid & 15) << 2;  // output col in tile
  int ar_ = tid >> 2, ak_ = (tid & 3) << 2;   // A-tile load: row 0..63, k 0/4/8/12
  int bk_ = tid >> 4, bc_ = (tid & 15) << 2;  // B-tile load: k 0..15, col 0..60

  const float* Ap = A + (size_t)(bm + ar_) * K + ak_;
  const float* A2p = A2 ? A2 + (size_t)(bm + ar_) * K + ak_ : nullptr;
  const float* Bp = B + (size_t)bk_ * N + bn + bc_;

  float acc[4][4] = {{0.f}};

  for (int k0 = 0; k0 < K; k0 += 16) {
    float4 av = *(const float4*)(Ap + k0);
    if (A2p) {
      float4 a2 = *(const float4*)(A2p + k0);
      av.x *= a2.x; av.y *= a2.y; av.z *= a2.z; av.w *= a2.w;
    }
    float4 bv = *(const float4*)(Bp + (size_t)k0 * N);
    As[ak_ + 0][ar_] = av.x;
    As[ak_ + 1][ar_] = av.y;
    As[ak_ + 2][ar_] = av.z;
    As[ak_ + 3][ar_] = av.w;
    *(float4*)&Bs[bk_][bc_] = bv;
    __syncthreads();
#pragma unroll
    for (int kk = 0; kk < 16; ++kk) {
      float4 a4 = *(const float4*)&As[kk][tr];
      float4 b4 = *(const float4*)&Bs[kk][tc];
      acc[0][0] += a4.x * b4.x; acc[0][1] += a4.x * b4.y;
      acc[0][2] += a4.x * b4.z; acc[0][3] += a4.x * b4.w;
      acc[1][0] += a4.y * b4.x; acc[1][1] += a4.y * b4.y;
      acc[1][2] += a4.y * b4.z; acc[1][3] += a4.y * b4.w;
      acc[2][0] += a4.z * b4.x; acc[2][1] += a4.z * b4.y;
      acc[2][2] += a4.z * b4.z; acc[2][3] += a4.z * b4.w;
      acc[3][0] += a4.w * b4.x; acc[3][1] += a4.w * b4.y;
      acc[3][2] += a4.w * b4.z; acc[3][3] += a4.w * b4.w;
    }
    __syncthreads();
  }

  float bb0 = 0.f, bb1 = 0.f, bb2 = 0.f, bb3 = 0.f;
  if (bias) {
    float4 b4 = *(const float4*)(bias + bn + tc);
    bb0 = b4.x; bb1 = b4.y; bb2 = b4.z; bb3 = b4.w;
  }
#pragma unroll
  for (int i2 = 0; i2 < 4; ++i2) {
    size_t idx = (size_t)(bm + tr + i2) * N + bn + tc;
    float r0 = 0.f, r1 = 0.f, r2 = 0.f, r3 = 0.f;
    if (res) {
      float4 r4 = *(const float4*)(res + idx);
      r0 = r4.x; r1 = r4.y; r2 = r4.z; r3 = r4.w;
    }
    float v0 = acc[i2][0] * scale + bb0;
    float v1 = acc[i2][1] * scale + bb1;
    float v2 = acc[i2][2] * scale + bb2;
    float v3 = acc[i2][3] * scale + bb3;
    if (do_sig) {
      v0 = 1.0f / (1.0f + __expf(-v0));
      v1 = 1.0f / (1.0f + __expf(-v1));
      v2 = 1.0f / (1.0f + __expf(-v2));
      v3 = 1.0f / (1.0f + __expf(-v3));
    }
    float4 ov;
    ov.x = v0 + r0; ov.y = v1 + r1; ov.z = v2 + r2; ov.w = v3 + r3;
    *(float4*)(Cmat + idx) = ov;
  }
}

// ---------------------------------------------------------------- row attention
// grid (R/32, H, S), 256 threads. thread t == key index. K rows in registers,
// V and 32 Q rows in padded LDS. q is pre-scaled by 1/sqrt(C).
__global__ __launch_bounds__(256) void row_attn_kernel(
    const float* __restrict__ q, const float* __restrict__ k,
    const float* __restrict__ v, const float* __restrict__ bias,
    float* __restrict__ o) {
  int s = blockIdx.z, h = blockIdx.y, q0 = blockIdx.x * 32;
  int t = threadIdx.x;
  int wid = t >> 6;
  __shared__ float Vs[R_][C_ + 1];
  __shared__ float Qs[32][C_ + 1];
  __shared__ float p_sh[R_];
  __shared__ float red[4];
  __shared__ float o_red[8][32];
  float kreg[C_];
  {
    const float* kp = k + ((size_t)(s * R_ + t) * H_ + h) * C_;
    const float* vp = v + ((size_t)(s * R_ + t) * H_ + h) * C_;
#pragma unroll
    for (int c = 0; c < C_; c += 4) {
      float4 kv = *(const float4*)(kp + c);
      kreg[c] = kv.x; kreg[c + 1] = kv.y; kreg[c + 2] = kv.z; kreg[c + 3] = kv.w;
      float4 vv = *(const float4*)(vp + c);
      Vs[t][c] = vv.x; Vs[t][c + 1] = vv.y; Vs[t][c + 2] = vv.z; Vs[t][c + 3] = vv.w;
    }
    int qrow = t >> 3, c0 = (t & 7) << 2;
    float4 qv = *(const float4*)(q + ((size_t)(s * R_ + q0 + qrow) * H_ + h) * C_ + c0);
    Qs[qrow][c0] = qv.x; Qs[qrow][c0 + 1] = qv.y;
    Qs[qrow][c0 + 2] = qv.z; Qs[qrow][c0 + 3] = qv.w;
  }
  __syncthreads();
  int gi = t >> 5, cc = t & 31;
  for (int j = 0; j < 32; ++j) {
    int qi = q0 + j;
    float logit = bias[((size_t)h * R_ + qi) * R_ + t];
#pragma unroll
    for (int c = 0; c < C_; ++c) logit += Qs[j][c] * kreg[c];
    // block softmax over 256 keys
    float wm = wave_max(logit);
    if ((t & 63) == 0) red[wid] = wm;
    __syncthreads();
    float mx = fmaxf(fmaxf(red[0], red[1]), fmaxf(red[2], red[3]));
    float e = __expf(logit - mx);
    __syncthreads();
    float ws = wave_sum(e);
    if ((t & 63) == 0) red[wid] = ws;
    __syncthreads();
    float inv = 1.0f / (red[0] + red[1] + red[2] + red[3]);
    p_sh[t] = e * inv;
    __syncthreads();
    // o[c] = sum_k p[k] * V[k][c]; 8 key-groups x 32 channels
    float part = 0.f;
#pragma unroll
    for (int kk = 0; kk < 32; ++kk)
      part += p_sh[gi * 32 + kk] * Vs[gi * 32 + kk][cc];
    o_red[gi][cc] = part;
    __syncthreads();
    if (t < 32) {
      float oc = 0.f;
#pragma unroll
      for (int g2 = 0; g2 < 8; ++g2) oc += o_red[g2][t];
      o[((size_t)(s * R_ + qi) * H_ + h) * C_ + t] = oc;
    }
    __syncthreads();
  }
}

// ---------------------------------------------------------------- column attention
// grid (H, R), 256 threads = 4 waves; keys are the S=64 dim (one wave = 64 keys).
__global__ __launch_bounds__(256) void col_attn_kernel(
    const float* __restrict__ q, const float* __restrict__ k,
    const float* __restrict__ v, float* __restrict__ o) {
  int h = blockIdx.x, r = blockIdx.y;
  int t = threadIdx.x;
  __shared__ float Qs[S_][C_ + 1], Ks[S_][C_ + 1], Vs[S_][C_ + 1];
  {
    int row = t >> 2;          // 0..63
    int c0 = (t & 3) << 3;     // 0,8,16,24
    size_t gbase = ((size_t)(row * R_ + r) * H_ + h) * C_ + c0;
    float4 x0 = *(const float4*)(q + gbase), x1 = *(const float4*)(q + gbase + 4);
    Qs[row][c0 + 0] = x0.x; Qs[row][c0 + 1] = x0.y; Qs[row][c0 + 2] = x0.z; Qs[row][c0 + 3] = x0.w;
    Qs[row][c0 + 4] = x1.x; Qs[row][c0 + 5] = x1.y; Qs[row][c0 + 6] = x1.z; Qs[row][c0 + 7] = x1.w;
    x0 = *(const float4*)(k + gbase); x1 = *(const float4*)(k + gbase + 4);
    Ks[row][c0 + 0] = x0.x; Ks[row][c0 + 1] = x0.y; Ks[row][c0 + 2] = x0.z; Ks[row][c0 + 3] = x0.w;
    Ks[row][c0 + 4] = x1.x; Ks[row][c0 + 5] = x1.y; Ks[row][c0 + 6] = x1.z; Ks[row][c0 + 7] = x1.w;
    x0 = *(const float4*)(v + gbase); x1 = *(const float4*)(v + gbase + 4);
    Vs[row][c0 + 0] = x0.x; Vs[row][c0 + 1] = x0.y; Vs[row][c0 + 2] = x0.z; Vs[row][c0 + 3] = x0.w;
    Vs[row][c0 + 4] = x1.x; Vs[row][c0 + 5] = x1.y; Vs[row][c0 + 6] = x1.z; Vs[row][c0 + 7] = x1.w;
  }
  __syncthreads();
  int w = t >> 6, lane = t & 63;
  int half = lane >> 5, cc = lane & 31;
  for (int i = 0; i < 16; ++i) {
    int qi = (i << 2) + w;  // each wave owns 16 query rows
    float logit = 0.f;
#pragma unroll
    for (int c = 0; c < C_; ++c) logit += Qs[qi][c] * Ks[lane][c];
    float mx = wave_max(logit);
    float e = __expf(logit - mx);
    float sum = wave_sum(e);
    float p = e / sum;
    // o[c] = sum_k p[k]*V[k][c]; lane = half*32+c, halves summed via xor-32
    float part = 0.f;
#pragma unroll
    for (int kk = 0; kk < 32; ++kk) {
      float pk = __shfl(p, half * 32 + kk);
      part += pk * Vs[half * 32 + kk][cc];
    }
    part += __shfl_xor(part, 32);
    if (half == 0)
      o[((size_t)(qi * R_ + r) * H_ + h) * C_ + cc] = part;
  }
}

// ---------------------------------------------------------------- launch
extern "C" void kernel_launch(void* const* d_in, const int* in_sizes, int n_in,
                              void* d_out, int out_size, void* d_ws, size_t ws_size,
                              hipStream_t stream) {
  const float* msa_in    = (const float*)d_in[0];
  const float* pair      = (const float*)d_in[1];
  const float* ln_row_s  = (const float*)d_in[2];
  const float* ln_row_b  = (const float*)d_in[3];
  const float* ln_pair_s = (const float*)d_in[4];
  const float* ln_pair_b = (const float*)d_in[5];
  const float* Wq  = (const float*)d_in[6];
  const float* Wk  = (const float*)d_in[7];
  const float* Wv  = (const float*)d_in[8];
  const float* Wb  = (const float*)d_in[9];
  const float* Wg  = (const float*)d_in[10];
  const float* bg  = (const float*)d_in[11];
  const float* Wo  = (const float*)d_in[12];
  const float* bo  = (const float*)d_in[13];
  const float* ln_col_s = (const float*)d_in[14];
  const float* ln_col_b = (const float*)d_in[15];
  const float* Wq2 = (const float*)d_in[16];
  const float* Wk2 = (const float*)d_in[17];
  const float* Wv2 = (const float*)d_in[18];
  const float* Wg2 = (const float*)d_in[19];
  const float* bg2 = (const float*)d_in[20];
  const float* Wo2 = (const float*)d_in[21];
  const float* bo2 = (const float*)d_in[22];
  const float* W_single = (const float*)d_in[23];
  const float* b_single = (const float*)d_in[24];
  float* out = (float*)d_out;

  // workspace layout (floats): msa | m(/o alias) | q | k | v | g | bias
  float* msa   = (float*)d_ws;
  float* m     = msa + SRE;
  float* qb    = m + SRE;
  float* kb    = qb + SRE;
  float* vb    = kb + SRE;
  float* gb    = vb + SRE;
  float* biasb = gb + SRE;    // H_*R_*R_
  float* ob    = m;           // o reuses m (m dead after projections)

  hipMemcpyAsync(msa, msa_in, (size_t)SRE * sizeof(float),
                 hipMemcpyDeviceToDevice, stream);

  const int SR = S_ * R_;
  dim3 gproj(HC_ / 64, SR / 64);   // projection GEMMs [SR,E]@[E,HC]
  dim3 gout(E_ / 64, SR / 64);     // out-proj [SR,HC]@[HC,E]

  for (int i = 0; i < NB_; ++i) {
    size_t wOff = (size_t)i * E_ * HC_;
    // ---------- row attention ----------
    ln256_kernel<<<SR, 256, 0, stream>>>(msa, ln_row_s + i * E_, ln_row_b + i * E_, m);
    gemm_kernel<<<gproj, 256, 0, stream>>>(m, nullptr, Wq + wOff, nullptr, nullptr, qb,
                                           SR, HC_, E_, QSCALE, 0);
    gemm_kernel<<<gproj, 256, 0, stream>>>(m, nullptr, Wk + wOff, nullptr, nullptr, kb,
                                           SR, HC_, E_, 1.0f, 0);
    gemm_kernel<<<gproj, 256, 0, stream>>>(m, nullptr, Wv + wOff, nullptr, nullptr, vb,
                                           SR, HC_, E_, 1.0f, 0);
    gemm_kernel<<<gproj, 256, 0, stream>>>(m, nullptr, Wg + wOff, bg + (size_t)i * HC_,
                                           nullptr, gb, SR, HC_, E_, 1.0f, 1);
    pair_bias_kernel<<<R_ * R_, 128, 0, stream>>>(pair, ln_pair_s + i * P_,
                                                  ln_pair_b + i * P_,
                                                  Wb + (size_t)i * P_ * H_, biasb);
    row_attn_kernel<<<dim3(R_ / 32, H_, S_), 256, 0, stream>>>(qb, kb, vb, biasb, ob);
    gemm_kernel<<<gout, 256, 0, stream>>>(ob, gb, Wo + wOff, bo + (size_t)i * E_,
                                          msa, msa, SR, E_, HC_, 1.0f, 0);
    // ---------- column attention ----------
    ln256_kernel<<<SR, 256, 0, stream>>>(msa, ln_col_s + i * E_, ln_col_b + i * E_, m);
    gemm_kernel<<<gproj, 256, 0, stream>>>(m, nullptr, Wq2 + wOff, nullptr, nullptr, qb,
                                           SR, HC_, E_, QSCALE, 0);
    gemm_kernel<<<gproj, 256, 0, stream>>>(m, nullptr, Wk2 + wOff, nullptr, nullptr, kb,
                                           SR, HC_, E_, 1.0f, 0);
    gemm_kernel<<<gproj, 256, 0, stream>>>(m, nullptr, Wv2 + wOff, nullptr, nullptr, vb,
                                           SR, HC_, E_, 1.0f, 0);
    gemm_kernel<<<gproj, 256, 0, stream>>>(m, nullptr, Wg2 + wOff, bg2 + (size_t)i * HC_,
                                           nullptr, gb, SR, HC_, E_, 1.0f, 1);
    col_attn_kernel<<<dim3(H_, R_), 256, 0, stream>>>(qb, kb, vb, ob);
    gemm_kernel<<<gout, 256, 0, stream>>>(ob, gb, Wo2 + wOff, bo2 + (size_t)i * E_,
                                          msa, msa, SR, E_, HC_, 1.0f, 0);
  }
  // ---------- final single projection: msa[0] @ W_single + b_single ----------
  gemm_kernel<<<dim3(SGL_ / 64, R_ / 64), 256, 0, stream>>>(
      msa, nullptr, W_single, b_single, nullptr, out, R_, SGL_, E_, 1.0f, 0);
}

// Round 3
// 1386.439 us; speedup vs baseline: 1.4719x; 1.4719x over previous
//
#include <hip/hip_runtime.h>
#include <hip/hip_bf16.h>
#include <math.h>

// Problem constants
#define S_ 64
#define R_ 256
#define E_ 256
#define P_ 128
#define H_ 8
#define C_ 32
#define NB_ 2
#define SGL_ 384
#define HC_ 256                 // H_*C_
#define SRE (S_ * R_ * E_)      // 4194304

static constexpr float QSCALE = 0.17677669529663687f;  // 1/sqrt(C_)

typedef __attribute__((ext_vector_type(8))) short short8;   // 8 bf16 (4 VGPRs)
typedef __attribute__((ext_vector_type(4))) float f32x4;

// bf16 <-> f32 bit helpers (round-to-nearest-even)
__device__ __forceinline__ float b2f(short s) {
  union { float f; unsigned u; } x; x.u = ((unsigned)(unsigned short)s) << 16; return x.f;
}
__device__ __forceinline__ short f2b(float f) {
  union { float f; unsigned u; } x; x.f = f;
  unsigned r = x.u + 0x7fff + ((x.u >> 16) & 1);
  return (short)(r >> 16);
}

// ---------------------------------------------------------------- reductions
__device__ __forceinline__ float wave_sum(float x) {
#pragma unroll
  for (int off = 32; off >= 1; off >>= 1) x += __shfl_xor(x, off);
  return x;
}
__device__ __forceinline__ float wave_max(float x) {
#pragma unroll
  for (int off = 32; off >= 1; off >>= 1) x = fmaxf(x, __shfl_xor(x, off));
  return x;
}

// ---------------------------------------------------------------- LayerNorm over 256 feats -> bf16
__global__ __launch_bounds__(256) void ln256_kernel(
    const float* __restrict__ x, const float* __restrict__ sc,
    const float* __restrict__ bi, short* __restrict__ out) {
  int row = blockIdx.x;
  int t = threadIdx.x;
  size_t base = (size_t)row * 256 + t;
  float v = x[base];
  __shared__ float red[4];
  float s1 = wave_sum(v);
  if ((t & 63) == 0) red[t >> 6] = s1;
  __syncthreads();
  float mu = (red[0] + red[1] + red[2] + red[3]) * (1.0f / 256.0f);
  float d = v - mu;
  __syncthreads();
  float s2 = wave_sum(d * d);
  if ((t & 63) == 0) red[t >> 6] = s2;
  __syncthreads();
  float var = (red[0] + red[1] + red[2] + red[3]) * (1.0f / 256.0f);
  out[base] = f2b(sc[t] * d * rsqrtf(var + 1e-5f) + bi[t]);
}

// ---------------------------------------------------------------- pair bias (fp32 out)
__global__ __launch_bounds__(128) void pair_bias_kernel(
    const float* __restrict__ pair, const float* __restrict__ sc,
    const float* __restrict__ bi, const float* __restrict__ Wb,
    float* __restrict__ bias_out) {
  int qk = blockIdx.x;
  int t = threadIdx.x;  // 0..127 == P index
  float v = pair[(size_t)qk * P_ + t];
  __shared__ float red[2];
  float s1 = wave_sum(v);
  if ((t & 63) == 0) red[t >> 6] = s1;
  __syncthreads();
  float mu = (red[0] + red[1]) * (1.0f / 128.0f);
  float d = v - mu;
  __syncthreads();
  float s2 = wave_sum(d * d);
  if ((t & 63) == 0) red[t >> 6] = s2;
  __syncthreads();
  float var = (red[0] + red[1]) * (1.0f / 128.0f);
  float z = sc[t] * d * rsqrtf(var + 1e-5f) + bi[t];

  __shared__ float hred[2][H_];
  const float* wp = Wb + (size_t)t * H_;
#pragma unroll
  for (int h = 0; h < H_; ++h) {
    float r = wave_sum(z * wp[h]);
    if ((t & 63) == 0) hred[t >> 6][h] = r;
  }
  __syncthreads();
  if (t < H_) bias_out[(size_t)t * (R_ * R_) + qk] = hred[0][t] + hred[1][t];
}

// ---------------------------------------------------------------- weight transpose+cvt
// 20 mats [256,256] fp32 -> wT[mi][n][k] bf16
__global__ __launch_bounds__(256) void wt_kernel(
    const float* w0, const float* w1, const float* w2, const float* w3, const float* w4,
    const float* w5, const float* w6, const float* w7, const float* w8, const float* w9,
    short* __restrict__ wT) {
  int mi = blockIdx.y;
  int b = mi >> 1, blk = mi & 1;
  const float* srcs[10] = {w0, w1, w2, w3, w4, w5, w6, w7, w8, w9};
  const float* src = srcs[b] + blk * 65536;
  int n = blockIdx.x, k = threadIdx.x;
  wT[(size_t)mi * 65536 + n * 256 + k] = f2b(src[k * 256 + n]);
}
// W_single [256,384] -> wsT[384][256]
__global__ __launch_bounds__(256) void wst_kernel(const float* __restrict__ w, short* __restrict__ o) {
  int n = blockIdx.x, k = threadIdx.x;
  o[n * 256 + k] = f2b(w[k * SGL_ + n]);
}

// ---------------------------------------------------------------- in-place row softmax
// VPL: values per lane (row length = VPL*64). One wave per row, 4 rows/block.
template <int VPL>
__global__ __launch_bounds__(256) void softmax_kernel(float* __restrict__ x) {
  int wave = threadIdx.x >> 6, lane = threadIdx.x & 63;
  size_t row = (size_t)blockIdx.x * 4 + wave;
  float* p = x + row * (VPL * 64);
  float v[VPL];
  if constexpr (VPL == 4) {
    float4 t = *(const float4*)(p + lane * 4);
    v[0] = t.x; v[1] = t.y; v[2] = t.z; v[3] = t.w;
  } else {
    v[0] = p[lane];
  }
  float m = v[0];
#pragma unroll
  for (int i = 1; i < VPL; ++i) m = fmaxf(m, v[i]);
  m = wave_max(m);
  float s = 0.f;
#pragma unroll
  for (int i = 0; i < VPL; ++i) { v[i] = __expf(v[i] - m); s += v[i]; }
  s = wave_sum(s);
  float inv = 1.0f / s;
  if constexpr (VPL == 4) {
    float4 t; t.x = v[0] * inv; t.y = v[1] * inv; t.z = v[2] * inv; t.w = v[3] * inv;
    *(float4*)(p + lane * 4) = t;
  } else {
    p[lane] = v[0] * inv;
  }
}

// ---------------------------------------------------------------- batched MFMA GEMM
// C = act(scale*(A[.*A2])@Bt^T + biasN + res); A: bf16 (AMODE0), bf16*bf16 gated
// (AMODE1), fp32->bf16 cvt (AMODE2). Bt is pre-transposed [N][K] bf16.
// Per-operand batch offset: off = (z>>sh)*hi + (z&msk)*lo (elements).
// CMODE: 0 normal row*ldC+col; 1 write [S][H][C][R] (v row); 2 write [R][H][C][S] (v col)
struct BOff { long long hi; int sh; int msk; int lo; };
__device__ __forceinline__ long long boff(const BOff& o, int z) {
  return (long long)(z >> o.sh) * o.hi + (long long)(z & o.msk) * o.lo;
}

template <int BM, int BN, int WR, int WC, int AMODE, int CMODE, bool OBF>
__global__ __launch_bounds__(256) void mgemm(
    const void* __restrict__ Av, const void* __restrict__ A2v,
    const short* __restrict__ Bt,
    const float* __restrict__ biasN, const float* resv,
    void* Cv,
    int N, int K, int ldA, int ldB, int ldC, int ldRes,
    BOff ao, BOff bo_, BOff co, BOff ro, float scale, int do_sig) {
  constexpr int WM = BM / WR, WN = BN / WC, FM = WM / 16, FN = WN / 16;
  __shared__ short As[BM][40];  // BK=32 + 8 pad (80B row stride, 16B aligned)
  __shared__ short Bs[BN][40];
  const int tid = threadIdx.x;
  const int lane = tid & 63, wave = tid >> 6;
  const int wr = wave / WC, wc = wave % WC;
  const int z = blockIdx.z;
  const int bm = blockIdx.y * BM, bn = blockIdx.x * BN;
  const long long aO = boff(ao, z), bO = boff(bo_, z), cO = boff(co, z);
  const long long rO = resv ? boff(ro, z) : 0;
  const int r16 = lane & 15, kg8 = (lane >> 4) * 8;

  f32x4 acc[FM][FN] = {};

  for (int k0 = 0; k0 < K; k0 += 32) {
    // stage A tile [BM][32]
#pragma unroll
    for (int c = tid; c < BM * 4; c += 256) {
      int row = c >> 2, k8 = (c & 3) * 8;
      long long gi = aO + (long long)(bm + row) * ldA + k0 + k8;
      short8 val;
      if constexpr (AMODE == 0) {
        val = *(const short8*)((const short*)Av + gi);
      } else if constexpr (AMODE == 1) {
        short8 x = *(const short8*)((const short*)Av + gi);
        short8 y = *(const short8*)((const short*)A2v + gi);
#pragma unroll
        for (int j = 0; j < 8; ++j) val[j] = f2b(b2f(x[j]) * b2f(y[j]));
      } else {
        const float* pf = (const float*)Av + gi;
        float4 f0 = *(const float4*)pf, f1 = *(const float4*)(pf + 4);
        val[0] = f2b(f0.x); val[1] = f2b(f0.y); val[2] = f2b(f0.z); val[3] = f2b(f0.w);
        val[4] = f2b(f1.x); val[5] = f2b(f1.y); val[6] = f2b(f1.z); val[7] = f2b(f1.w);
      }
      *(short8*)&As[row][k8] = val;
    }
    // stage B tile [BN][32]
#pragma unroll
    for (int c = tid; c < BN * 4; c += 256) {
      int row = c >> 2, k8 = (c & 3) * 8;
      *(short8*)&Bs[row][k8] =
          *(const short8*)(Bt + bO + (long long)(bn + row) * ldB + k0 + k8);
    }
    __syncthreads();
    short8 af[FM], bfr[FN];
#pragma unroll
    for (int f = 0; f < FM; ++f) af[f] = *(const short8*)&As[wr * WM + f * 16 + r16][kg8];
#pragma unroll
    for (int f = 0; f < FN; ++f) bfr[f] = *(const short8*)&Bs[wc * WN + f * 16 + r16][kg8];
#pragma unroll
    for (int i = 0; i < FM; ++i)
#pragma unroll
      for (int j = 0; j < FN; ++j)
        acc[i][j] = __builtin_amdgcn_mfma_f32_16x16x32_bf16(af[i], bfr[j], acc[i][j], 0, 0, 0);
    __syncthreads();
  }

  // epilogue: D col = lane&15, row = (lane>>4)*4 + r   [m89-verified]
#pragma unroll
  for (int i = 0; i < FM; ++i) {
#pragma unroll
    for (int j = 0; j < FN; ++j) {
      int col = bn + wc * WN + j * 16 + r16;
      float bN = biasN ? biasN[col] : 0.0f;
#pragma unroll
      for (int r = 0; r < 4; ++r) {
        int row = bm + wr * WM + i * 16 + (lane >> 4) * 4 + r;
        float v = acc[i][j][r] * scale + bN;
        if (resv) v += resv[rO + (long long)row * ldRes + col];
        if (do_sig) v = 1.0f / (1.0f + __expf(-v));
        long long addr;
        if constexpr (CMODE == 0)
          addr = cO + (long long)row * ldC + col;
        else if constexpr (CMODE == 1)
          addr = (((long long)(row >> 8) * H_ + (col >> 5)) * C_ + (col & 31)) * R_ + (row & 255);
        else
          addr = (((long long)(row & 255) * H_ + (col >> 5)) * C_ + (col & 31)) * S_ + (row >> 8);
        if constexpr (OBF) ((short*)Cv)[addr] = f2b(v);
        else ((float*)Cv)[addr] = v;
      }
    }
  }
}

// ---------------------------------------------------------------- launch
extern "C" void kernel_launch(void* const* d_in, const int* in_sizes, int n_in,
                              void* d_out, int out_size, void* d_ws, size_t ws_size,
                              hipStream_t stream) {
  const float* msa_in    = (const float*)d_in[0];
  const float* pair      = (const float*)d_in[1];
  const float* ln_row_s  = (const float*)d_in[2];
  const float* ln_row_b  = (const float*)d_in[3];
  const float* ln_pair_s = (const float*)d_in[4];
  const float* ln_pair_b = (const float*)d_in[5];
  const float* Wq  = (const float*)d_in[6];
  const float* Wk  = (const float*)d_in[7];
  const float* Wv  = (const float*)d_in[8];
  const float* Wb  = (const float*)d_in[9];
  const float* Wg  = (const float*)d_in[10];
  const float* bg  = (const float*)d_in[11];
  const float* Wo  = (const float*)d_in[12];
  const float* bo  = (const float*)d_in[13];
  const float* ln_col_s = (const float*)d_in[14];
  const float* ln_col_b = (const float*)d_in[15];
  const float* Wq2 = (const float*)d_in[16];
  const float* Wk2 = (const float*)d_in[17];
  const float* Wv2 = (const float*)d_in[18];
  const float* Wg2 = (const float*)d_in[19];
  const float* bg2 = (const float*)d_in[20];
  const float* Wo2 = (const float*)d_in[21];
  const float* bo2 = (const float*)d_in[22];
  const float* W_single = (const float*)d_in[23];
  const float* b_single = (const float*)d_in[24];
  float* out = (float*)d_out;

  // workspace carve (~97 MB total; m_bf aliases head of lg — m dead once attn starts)
  float* msa  = (float*)d_ws;                 // 4.19M f32
  short* q_bf = (short*)(msa + SRE);          // bf16 buffers, 4.19M each
  short* k_bf = q_bf + SRE;
  short* vt_bf = k_bf + SRE;                  // V pre-transposed for PV
  short* g_bf = vt_bf + SRE;
  short* o_bf = g_bf + SRE;
  float* biasb = (float*)(o_bf + SRE);        // [H][R][R] f32
  short* wT  = (short*)(biasb + H_ * R_ * R_);// 20 x [256][256] bf16 (B^T)
  short* wsT = wT + 20 * 65536;               // [384][256] bf16
  short* m_bf = wsT + SGL_ * E_;              // LN output (aliased w/ lg)
  float* lg  = (float*)m_bf;                  // logits chunk: 16*8*65536 f32 = 33.5MB

  hipMemcpyAsync(msa, msa_in, (size_t)SRE * sizeof(float),
                 hipMemcpyDeviceToDevice, stream);
  wt_kernel<<<dim3(256, 20), 256, 0, stream>>>(Wq, Wk, Wv, Wg, Wo,
                                               Wq2, Wk2, Wv2, Wg2, Wo2, wT);
  wst_kernel<<<384, 256, 0, stream>>>(W_single, wsT);

  const int SR = S_ * R_;
  const BOff Z{0, 0, 0, 0};
  dim3 gproj(2, SR / 128);  // [16384,256] @ [256,256]

  for (int i = 0; i < NB_; ++i) {
    // ================= row attention =================
    ln256_kernel<<<SR, 256, 0, stream>>>(msa, ln_row_s + i * E_, ln_row_b + i * E_, m_bf);
    mgemm<128,128,2,2,0,0,true><<<gproj, 256, 0, stream>>>(
        m_bf, nullptr, wT + (0 + i) * 65536, nullptr, nullptr, q_bf,
        256, 256, 256, 256, 256, 0, Z, Z, Z, Z, 1.f, 0);
    mgemm<128,128,2,2,0,0,true><<<gproj, 256, 0, stream>>>(
        m_bf, nullptr, wT + (2 + i) * 65536, nullptr, nullptr, k_bf,
        256, 256, 256, 256, 256, 0, Z, Z, Z, Z, 1.f, 0);
    mgemm<128,128,2,2,0,1,true><<<gproj, 256, 0, stream>>>(        // V -> [S][H][C][R]
        m_bf, nullptr, wT + (4 + i) * 65536, nullptr, nullptr, vt_bf,
        256, 256, 256, 256, 256, 0, Z, Z, Z, Z, 1.f, 0);
    mgemm<128,128,2,2,0,0,true><<<gproj, 256, 0, stream>>>(        // gate: sigmoid(.+bg)
        m_bf, nullptr, wT + (6 + i) * 65536, bg + (size_t)i * HC_, nullptr, g_bf,
        256, 256, 256, 256, 256, 0, Z, Z, Z, Z, 1.f, 1);
    pair_bias_kernel<<<R_ * R_, 128, 0, stream>>>(
        pair, ln_pair_s + i * P_, ln_pair_b + i * P_, Wb + (size_t)i * P_ * H_, biasb);

    for (int c4 = 0; c4 < 4; ++c4) {             // s-chunks of 16
      long long so = (long long)c4 * 16 * 65536;
      BOff aQ{65536, 3, 7, 32};                  // z=(s_loc,h): (z>>3)*65536+(z&7)*32
      BOff cL{65536, 0, 0, 0};
      BOff rB{0, 0, 7, 65536};                   // bias slice by h
      mgemm<128,128,2,2,0,0,false><<<dim3(2, 2, 128), 256, 0, stream>>>(
          q_bf + so, nullptr, k_bf + so, nullptr, biasb, lg,
          256, 256, 256, 256, 256, 256, aQ, aQ, cL, rB, QSCALE, 0);
      softmax_kernel<4><<<8192, 256, 0, stream>>>(lg);             // in-place, rows of 256
      BOff aP{65536, 0, 0, 0}, bV{8192, 0, 0, 0}, cO{65536, 3, 7, 32};
      mgemm<128,32,4,1,2,0,true><<<dim3(1, 2, 128), 256, 0, stream>>>(
          lg, nullptr, vt_bf + so, nullptr, nullptr, o_bf + so,
          32, 256, 256, 256, 256, 0, aP, bV, cO, Z, 1.f, 0);
    }
    mgemm<128,128,2,2,1,0,false><<<gproj, 256, 0, stream>>>(       // (sig(g).*o)@Wo+bo+msa
        o_bf, g_bf, wT + (8 + i) * 65536, bo + (size_t)i * E_, msa, msa,
        256, 256, 256, 256, 256, 256, Z, Z, Z, Z, 1.f, 0);

    // ================= column attention =================
    ln256_kernel<<<SR, 256, 0, stream>>>(msa, ln_col_s + i * E_, ln_col_b + i * E_, m_bf);
    mgemm<128,128,2,2,0,0,true><<<gproj, 256, 0, stream>>>(
        m_bf, nullptr, wT + (10 + i) * 65536, nullptr, nullptr, q_bf,
        256, 256, 256, 256, 256, 0, Z, Z, Z, Z, 1.f, 0);
    mgemm<128,128,2,2,0,0,true><<<gproj, 256, 0, stream>>>(
        m_bf, nullptr, wT + (12 + i) * 65536, nullptr, nullptr, k_bf,
        256, 256, 256, 256, 256, 0, Z, Z, Z, Z, 1.f, 0);
    mgemm<128,128,2,2,0,2,true><<<gproj, 256, 0, stream>>>(        // V -> [R][H][C][S]
        m_bf, nullptr, wT + (14 + i) * 65536, nullptr, nullptr, vt_bf,
        256, 256, 256, 256, 256, 0, Z, Z, Z, Z, 1.f, 0);
    mgemm<128,128,2,2,0,0,true><<<gproj, 256, 0, stream>>>(
        m_bf, nullptr, wT + (16 + i) * 65536, bg2 + (size_t)i * HC_, nullptr, g_bf,
        256, 256, 256, 256, 256, 0, Z, Z, Z, Z, 1.f, 1);
    {
      BOff aC{256, 3, 7, 32};                    // z=(r,h): (z>>3)*256+(z&7)*32
      BOff cL2{4096, 0, 0, 0};
      mgemm<64,64,2,2,0,0,false><<<dim3(1, 1, 2048), 256, 0, stream>>>(
          q_bf, nullptr, k_bf, nullptr, nullptr, lg,
          64, 32, 65536, 65536, 64, 0, aC, aC, cL2, Z, QSCALE, 0);
      softmax_kernel<1><<<32768, 256, 0, stream>>>(lg);            // rows of 64
      BOff aP2{4096, 0, 0, 0}, bV2{2048, 0, 0, 0}, cO2{256, 3, 7, 32};
      mgemm<64,32,2,2,2,0,true><<<dim3(1, 1, 2048), 256, 0, stream>>>(
          lg, nullptr, vt_bf, nullptr, nullptr, o_bf,
          32, 64, 64, 64, 65536, 0, aP2, bV2, cO2, Z, 1.f, 0);
    }
    mgemm<128,128,2,2,1,0,false><<<gproj, 256, 0, stream>>>(
        o_bf, g_bf, wT + (18 + i) * 65536, bo2 + (size_t)i * E_, msa, msa,
        256, 256, 256, 256, 256, 256, Z, Z, Z, Z, 1.f, 0);
  }

  // final: single = msa[0] @ W_single + b_single   [256,384]
  mgemm<128,128,2,2,2,0,false><<<dim3(3, 2), 256, 0, stream>>>(
      msa, nullptr, wsT, b_single, nullptr, out,
      384, 256, 256, 256, 384, 0, Z, Z, Z, Z, 1.f, 0);
}

// Round 8
// 1147.593 us; speedup vs baseline: 1.7783x; 1.2081x over previous
//
#include <hip/hip_runtime.h>
#include <hip/hip_bf16.h>
#include <math.h>

// Problem constants
#define S_ 64
#define R_ 256
#define E_ 256
#define P_ 128
#define H_ 8
#define C_ 32
#define NB_ 2
#define SGL_ 384
#define HC_ 256                 // H_*C_
#define SRE (S_ * R_ * E_)      // 4194304

static constexpr float QSCALE = 0.17677669529663687f;  // 1/sqrt(C_)

typedef __attribute__((ext_vector_type(8))) short short8;   // 8 bf16 (4 VGPRs)
typedef __attribute__((ext_vector_type(4))) short short4v;  // 4 bf16
typedef __attribute__((ext_vector_type(4))) float f32x4;

// bf16 <-> f32 bit helpers (round-to-nearest-even)
__device__ __forceinline__ float b2f(short s) {
  union { float f; unsigned u; } x; x.u = ((unsigned)(unsigned short)s) << 16; return x.f;
}
__device__ __forceinline__ short f2b(float f) {
  union { float f; unsigned u; } x; x.f = f;
  unsigned r = x.u + 0x7fff + ((x.u >> 16) & 1);
  return (short)(r >> 16);
}

// ---------------------------------------------------------------- reductions
__device__ __forceinline__ float wave_sum(float x) {
#pragma unroll
  for (int off = 32; off >= 1; off >>= 1) x += __shfl_xor(x, off);
  return x;
}

// ---------------------------------------------------------------- LayerNorm 256 -> bf16
// wave per row, no barriers, grid-stride
__global__ __launch_bounds__(256) void ln256_kernel(
    const float* __restrict__ x, const float* __restrict__ sc,
    const float* __restrict__ bi, short* __restrict__ out, int nrows) {
  int lane = threadIdx.x & 63, wv = threadIdx.x >> 6;
  float4 s4 = *(const float4*)(sc + lane * 4);
  float4 b4 = *(const float4*)(bi + lane * 4);
  for (int row = blockIdx.x * 4 + wv; row < nrows; row += gridDim.x * 4) {
    float4 v = *(const float4*)(x + (size_t)row * 256 + lane * 4);
    float mu = wave_sum(v.x + v.y + v.z + v.w) * (1.0f / 256.0f);
    float dx = v.x - mu, dy = v.y - mu, dz = v.z - mu, dw = v.w - mu;
    float var = wave_sum(dx * dx + dy * dy + dz * dz + dw * dw) * (1.0f / 256.0f);
    float inv = rsqrtf(var + 1e-5f);
    short4v o;
    o[0] = f2b(s4.x * dx * inv + b4.x);
    o[1] = f2b(s4.y * dy * inv + b4.y);
    o[2] = f2b(s4.z * dz * inv + b4.z);
    o[3] = f2b(s4.w * dw * inv + b4.w);
    *(short4v*)(out + (size_t)row * 256 + lane * 4) = o;
  }
}

// ---------------------------------------------------------------- pair bias
// wave per (q,k) row: LN over P=128 (2 f32/lane) + 8 dot products, no barriers
__global__ __launch_bounds__(256) void pair_bias_kernel(
    const float* __restrict__ pair, const float* __restrict__ sc,
    const float* __restrict__ bi, const float* __restrict__ Wb,
    float* __restrict__ bias_out) {
  int lane = threadIdx.x & 63, wv = threadIdx.x >> 6;
  int e0 = lane * 2;
  float sc0 = sc[e0], sc1 = sc[e0 + 1], bi0 = bi[e0], bi1 = bi[e0 + 1];
  float w0[H_], w1[H_];
#pragma unroll
  for (int h = 0; h < H_; ++h) {
    w0[h] = Wb[e0 * H_ + h];
    w1[h] = Wb[(e0 + 1) * H_ + h];
  }
  for (int row = blockIdx.x * 4 + wv; row < R_ * R_; row += gridDim.x * 4) {
    float2 v = *(const float2*)(pair + (size_t)row * P_ + e0);
    float mu = wave_sum(v.x + v.y) * (1.0f / 128.0f);
    float dx = v.x - mu, dy = v.y - mu;
    float var = wave_sum(dx * dx + dy * dy) * (1.0f / 128.0f);
    float inv = rsqrtf(var + 1e-5f);
    float z0 = sc0 * dx * inv + bi0;
    float z1 = sc1 * dy * inv + bi1;
#pragma unroll
    for (int h = 0; h < H_; ++h) {
      float d = wave_sum(z0 * w0[h] + z1 * w1[h]);
      if (lane == h) bias_out[(size_t)h * (R_ * R_) + row] = d;
    }
  }
}

// ---------------------------------------------------------------- weight transpose+cvt
// 20 mats [256,256] fp32 -> wT[mi][n][k] bf16, LDS 64x64 tile transpose
__global__ __launch_bounds__(256) void wt_kernel(
    const float* w0, const float* w1, const float* w2, const float* w3, const float* w4,
    const float* w5, const float* w6, const float* w7, const float* w8, const float* w9,
    short* __restrict__ wT) {
  __shared__ float t_[64][65];
  int mi = blockIdx.z;
  const float* srcs[10] = {w0, w1, w2, w3, w4, w5, w6, w7, w8, w9};
  const float* src = srcs[mi >> 1] + (mi & 1) * 65536;
  int kb = (blockIdx.x & 3) * 64, nb = (blockIdx.x >> 2) * 64;
  int tx = threadIdx.x & 63, ty = threadIdx.x >> 6;
#pragma unroll
  for (int i = 0; i < 16; ++i) {
    int k = i * 4 + ty;
    t_[k][tx] = src[(kb + k) * 256 + nb + tx];
  }
  __syncthreads();
#pragma unroll
  for (int i = 0; i < 16; ++i) {
    int n = i * 4 + ty;
    wT[(size_t)mi * 65536 + (nb + n) * 256 + kb + tx] = f2b(t_[tx][n]);
  }
}
// W_single [256,384] -> wsT[384][256]
__global__ __launch_bounds__(256) void wst_kernel(const float* __restrict__ w, short* __restrict__ o) {
  __shared__ float t_[64][65];
  int kb = (blockIdx.x & 3) * 64, nb = (blockIdx.x >> 2) * 64;
  int tx = threadIdx.x & 63, ty = threadIdx.x >> 6;
#pragma unroll
  for (int i = 0; i < 16; ++i) {
    int k = i * 4 + ty;
    t_[k][tx] = w[(kb + k) * SGL_ + nb + tx];
  }
  __syncthreads();
#pragma unroll
  for (int i = 0; i < 16; ++i) {
    int n = i * 4 + ty;
    o[(nb + n) * 256 + kb + tx] = f2b(t_[tx][n]);
  }
}

// ---------------------------------------------------------------- in-place row softmax
// VPL: values per lane (row length = VPL*64). Wave per row, grid-stride.
template <int VPL>
__global__ __launch_bounds__(256) void softmax_kernel(float* __restrict__ x, int nrows) {
  int wv = threadIdx.x >> 6, lane = threadIdx.x & 63;
  for (int row = blockIdx.x * 4 + wv; row < nrows; row += gridDim.x * 4) {
    float* p = x + (size_t)row * (VPL * 64);
    float v[VPL];
    if constexpr (VPL == 4) {
      float4 t = *(const float4*)(p + lane * 4);
      v[0] = t.x; v[1] = t.y; v[2] = t.z; v[3] = t.w;
    } else {
      v[0] = p[lane];
    }
    float m = v[0];
#pragma unroll
    for (int i = 1; i < VPL; ++i) m = fmaxf(m, v[i]);
#pragma unroll
    for (int off = 32; off >= 1; off >>= 1) m = fmaxf(m, __shfl_xor(m, off));
    float s = 0.f;
#pragma unroll
    for (int i = 0; i < VPL; ++i) { v[i] = __expf(v[i] - m); s += v[i]; }
    s = wave_sum(s);
    float inv = 1.0f / s;
    if constexpr (VPL == 4) {
      float4 t; t.x = v[0] * inv; t.y = v[1] * inv; t.z = v[2] * inv; t.w = v[3] * inv;
      *(float4*)(p + lane * 4) = t;
    } else {
      p[lane] = v[0] * inv;
    }
  }
}

// ---------------------------------------------------------------- batched MFMA GEMM
// C = act(scale*(A[.*A2])@Bt^T + biasN + res); A: bf16 (AMODE0), bf16*bf16 gated
// (AMODE1), fp32->bf16 cvt (AMODE2). Bt is pre-transposed [N][K] bf16.
// Per-operand batch offset: off = (z>>sh)*hi + (z&msk)*lo (elements).
// CMODE: 0 normal row*ldC+col; 1 write [S][H][C][R] (v row); 2 write [R][H][C][S] (v col)
struct BOff { long long hi; int sh; int msk; int lo; };
__device__ __forceinline__ long long boff(const BOff& o, int z) {
  return (long long)(z >> o.sh) * o.hi + (long long)(z & o.msk) * o.lo;
}

template <int BM, int BN, int WR, int WC, int AMODE, int CMODE, bool OBF>
__global__ __launch_bounds__(256) void mgemm(
    const void* __restrict__ Av, const void* __restrict__ A2v,
    const short* __restrict__ Bt,
    const float* __restrict__ biasN, const float* resv,
    void* Cv,
    int N, int K, int ldA, int ldB, int ldC, int ldRes,
    BOff ao, BOff bo_, BOff co, BOff ro, float scale, int do_sig) {
  constexpr int WM = BM / WR, WN = BN / WC, FM = WM / 16, FN = WN / 16;
  __shared__ short As[BM][40];  // BK=32 + 8 pad (80B row stride, 16B aligned)
  __shared__ short Bs[BN][40];
  const int tid = threadIdx.x;
  const int lane = tid & 63, wave = tid >> 6;
  const int wr = wave / WC, wc = wave % WC;
  const int z = blockIdx.z;
  const int bm = blockIdx.y * BM, bn = blockIdx.x * BN;
  const long long aO = boff(ao, z), bO = boff(bo_, z), cO = boff(co, z);
  const long long rO = resv ? boff(ro, z) : 0;
  const int r16 = lane & 15, kg8 = (lane >> 4) * 8;

  f32x4 acc[FM][FN] = {};

  for (int k0 = 0; k0 < K; k0 += 32) {
    // stage A tile [BM][32]
#pragma unroll
    for (int c = tid; c < BM * 4; c += 256) {
      int row = c >> 2, k8 = (c & 3) * 8;
      long long gi = aO + (long long)(bm + row) * ldA + k0 + k8;
      short8 val;
      if constexpr (AMODE == 0) {
        val = *(const short8*)((const short*)Av + gi);
      } else if constexpr (AMODE == 1) {
        short8 x = *(const short8*)((const short*)Av + gi);
        short8 y = *(const short8*)((const short*)A2v + gi);
#pragma unroll
        for (int j = 0; j < 8; ++j) val[j] = f2b(b2f(x[j]) * b2f(y[j]));
      } else {
        const float* pf = (const float*)Av + gi;
        float4 f0 = *(const float4*)pf, f1 = *(const float4*)(pf + 4);
        val[0] = f2b(f0.x); val[1] = f2b(f0.y); val[2] = f2b(f0.z); val[3] = f2b(f0.w);
        val[4] = f2b(f1.x); val[5] = f2b(f1.y); val[6] = f2b(f1.z); val[7] = f2b(f1.w);
      }
      *(short8*)&As[row][k8] = val;
    }
    // stage B tile [BN][32]
#pragma unroll
    for (int c = tid; c < BN * 4; c += 256) {
      int row = c >> 2, k8 = (c & 3) * 8;
      *(short8*)&Bs[row][k8] =
          *(const short8*)(Bt + bO + (long long)(bn + row) * ldB + k0 + k8);
    }
    __syncthreads();
    short8 af[FM], bfr[FN];
#pragma unroll
    for (int f = 0; f < FM; ++f) af[f] = *(const short8*)&As[wr * WM + f * 16 + r16][kg8];
#pragma unroll
    for (int f = 0; f < FN; ++f) bfr[f] = *(const short8*)&Bs[wc * WN + f * 16 + r16][kg8];
#pragma unroll
    for (int i = 0; i < FM; ++i)
#pragma unroll
      for (int j = 0; j < FN; ++j)
        acc[i][j] = __builtin_amdgcn_mfma_f32_16x16x32_bf16(af[i], bfr[j], acc[i][j], 0, 0, 0);
    __syncthreads();
  }

  // epilogue: D col = lane&15, row = (lane>>4)*4 + r   [m89-verified]
#pragma unroll
  for (int i = 0; i < FM; ++i) {
#pragma unroll
    for (int j = 0; j < FN; ++j) {
      int col = bn + wc * WN + j * 16 + r16;
      float bN = biasN ? biasN[col] : 0.0f;
#pragma unroll
      for (int r = 0; r < 4; ++r) {
        int row = bm + wr * WM + i * 16 + (lane >> 4) * 4 + r;
        float v = acc[i][j][r] * scale + bN;
        if (resv) v += resv[rO + (long long)row * ldRes + col];
        if (do_sig) v = 1.0f / (1.0f + __expf(-v));
        long long addr;
        if constexpr (CMODE == 0)
          addr = cO + (long long)row * ldC + col;
        else if constexpr (CMODE == 1)
          addr = (((long long)(row >> 8) * H_ + (col >> 5)) * C_ + (col & 31)) * R_ + (row & 255);
        else
          addr = (((long long)(row & 255) * H_ + (col >> 5)) * C_ + (col & 31)) * S_ + (row >> 8);
        if constexpr (OBF) ((short*)Cv)[addr] = f2b(v);
        else ((float*)Cv)[addr] = v;
      }
    }
  }
}

// ---------------------------------------------------------------- launch
extern "C" void kernel_launch(void* const* d_in, const int* in_sizes, int n_in,
                              void* d_out, int out_size, void* d_ws, size_t ws_size,
                              hipStream_t stream) {
  const float* msa_in    = (const float*)d_in[0];
  const float* pair      = (const float*)d_in[1];
  const float* ln_row_s  = (const float*)d_in[2];
  const float* ln_row_b  = (const float*)d_in[3];
  const float* ln_pair_s = (const float*)d_in[4];
  const float* ln_pair_b = (const float*)d_in[5];
  const float* Wq  = (const float*)d_in[6];
  const float* Wk  = (const float*)d_in[7];
  const float* Wv  = (const float*)d_in[8];
  const float* Wb  = (const float*)d_in[9];
  const float* Wg  = (const float*)d_in[10];
  const float* bg  = (const float*)d_in[11];
  const float* Wo  = (const float*)d_in[12];
  const float* bo  = (const float*)d_in[13];
  const float* ln_col_s = (const float*)d_in[14];
  const float* ln_col_b = (const float*)d_in[15];
  const float* Wq2 = (const float*)d_in[16];
  const float* Wk2 = (const float*)d_in[17];
  const float* Wv2 = (const float*)d_in[18];
  const float* Wg2 = (const float*)d_in[19];
  const float* bg2 = (const float*)d_in[20];
  const float* Wo2 = (const float*)d_in[21];
  const float* bo2 = (const float*)d_in[22];
  const float* W_single = (const float*)d_in[23];
  const float* b_single = (const float*)d_in[24];
  float* out = (float*)d_out;

  // workspace carve (~94 MB total; m_bf aliases head of lg — m dead once attn starts)
  float* msa  = (float*)d_ws;                 // 4.19M f32
  short* q_bf = (short*)(msa + SRE);          // bf16 buffers, 4.19M each
  short* k_bf = q_bf + SRE;
  short* vt_bf = k_bf + SRE;                  // V pre-transposed for PV
  short* g_bf = vt_bf + SRE;
  short* o_bf = g_bf + SRE;
  float* biasb = (float*)(o_bf + SRE);        // [H][R][R] f32
  short* wT  = (short*)(biasb + H_ * R_ * R_);// 20 x [256][256] bf16 (B^T)
  short* wsT = wT + 20 * 65536;               // [384][256] bf16
  short* m_bf = wsT + SGL_ * E_;              // LN output (aliased w/ lg)
  float* lg  = (float*)m_bf;                  // logits chunk: 16*8*65536 f32 = 33.5MB

  hipMemcpyAsync(msa, msa_in, (size_t)SRE * sizeof(float),
                 hipMemcpyDeviceToDevice, stream);
  wt_kernel<<<dim3(16, 1, 20), 256, 0, stream>>>(Wq, Wk, Wv, Wg, Wo,
                                                 Wq2, Wk2, Wv2, Wg2, Wo2, wT);
  wst_kernel<<<24, 256, 0, stream>>>(W_single, wsT);

  const int SR = S_ * R_;
  const BOff Z{0, 0, 0, 0};
  dim3 gproj(2, SR / 128);  // [16384,256] @ [256,256]

  for (int i = 0; i < NB_; ++i) {
    // ================= row attention =================
    ln256_kernel<<<2048, 256, 0, stream>>>(msa, ln_row_s + i * E_, ln_row_b + i * E_, m_bf, SR);
    mgemm<128,128,2,2,0,0,true><<<gproj, 256, 0, stream>>>(
        m_bf, nullptr, wT + (0 + i) * 65536, nullptr, nullptr, q_bf,
        256, 256, 256, 256, 256, 0, Z, Z, Z, Z, 1.f, 0);
    mgemm<128,128,2,2,0,0,true><<<gproj, 256, 0, stream>>>(
        m_bf, nullptr, wT + (2 + i) * 65536, nullptr, nullptr, k_bf,
        256, 256, 256, 256, 256, 0, Z, Z, Z, Z, 1.f, 0);
    mgemm<128,128,2,2,0,1,true><<<gproj, 256, 0, stream>>>(        // V -> [S][H][C][R]
        m_bf, nullptr, wT + (4 + i) * 65536, nullptr, nullptr, vt_bf,
        256, 256, 256, 256, 256, 0, Z, Z, Z, Z, 1.f, 0);
    mgemm<128,128,2,2,0,0,true><<<gproj, 256, 0, stream>>>(        // gate: sigmoid(.+bg)
        m_bf, nullptr, wT + (6 + i) * 65536, bg + (size_t)i * HC_, nullptr, g_bf,
        256, 256, 256, 256, 256, 0, Z, Z, Z, Z, 1.f, 1);
    pair_bias_kernel<<<2048, 256, 0, stream>>>(
        pair, ln_pair_s + i * P_, ln_pair_b + i * P_, Wb + (size_t)i * P_ * H_, biasb);

    for (int c4 = 0; c4 < 4; ++c4) {             // s-chunks of 16
      long long so = (long long)c4 * 16 * 65536;
      BOff aQ{65536, 3, 7, 32};                  // z=(s_loc,h): (z>>3)*65536+(z&7)*32
      BOff cL{65536, 0, 0, 0};
      BOff rB{0, 0, 7, 65536};                   // bias slice by h
      mgemm<128,128,2,2,0,0,false><<<dim3(2, 2, 128), 256, 0, stream>>>(
          q_bf + so, nullptr, k_bf + so, nullptr, biasb, lg,
          256, 32, 256, 256, 256, 256, aQ, aQ, cL, rB, QSCALE, 0);   // K=32 (per-head)
      softmax_kernel<4><<<2048, 256, 0, stream>>>(lg, 32768);        // rows of 256
      BOff aP{65536, 0, 0, 0}, bV{8192, 0, 0, 0}, cO{65536, 3, 7, 32};
      mgemm<128,32,4,1,2,0,true><<<dim3(1, 2, 128), 256, 0, stream>>>(
          lg, nullptr, vt_bf + so, nullptr, nullptr, o_bf + so,
          32, 256, 256, 256, 256, 0, aP, bV, cO, Z, 1.f, 0);
    }
    mgemm<128,128,2,2,1,0,false><<<gproj, 256, 0, stream>>>(       // (sig(g).*o)@Wo+bo+msa
        o_bf, g_bf, wT + (8 + i) * 65536, bo + (size_t)i * E_, msa, msa,
        256, 256, 256, 256, 256, 256, Z, Z, Z, Z, 1.f, 0);

    // ================= column attention =================
    ln256_kernel<<<2048, 256, 0, stream>>>(msa, ln_col_s + i * E_, ln_col_b + i * E_, m_bf, SR);
    mgemm<128,128,2,2,0,0,true><<<gproj, 256, 0, stream>>>(
        m_bf, nullptr, wT + (10 + i) * 65536, nullptr, nullptr, q_bf,
        256, 256, 256, 256, 256, 0, Z, Z, Z, Z, 1.f, 0);
    mgemm<128,128,2,2,0,0,true><<<gproj, 256, 0, stream>>>(
        m_bf, nullptr, wT + (12 + i) * 65536, nullptr, nullptr, k_bf,
        256, 256, 256, 256, 256, 0, Z, Z, Z, Z, 1.f, 0);
    mgemm<128,128,2,2,0,2,true><<<gproj, 256, 0, stream>>>(        // V -> [R][H][C][S]
        m_bf, nullptr, wT + (14 + i) * 65536, nullptr, nullptr, vt_bf,
        256, 256, 256, 256, 256, 0, Z, Z, Z, Z, 1.f, 0);
    mgemm<128,128,2,2,0,0,true><<<gproj, 256, 0, stream>>>(
        m_bf, nullptr, wT + (16 + i) * 65536, bg2 + (size_t)i * HC_, nullptr, g_bf,
        256, 256, 256, 256, 256, 0, Z, Z, Z, Z, 1.f, 1);
    {
      BOff aC{256, 3, 7, 32};                    // z=(r,h): (z>>3)*256+(z&7)*32
      BOff cL2{4096, 0, 0, 0};
      mgemm<64,64,2,2,0,0,false><<<dim3(1, 1, 2048), 256, 0, stream>>>(
          q_bf, nullptr, k_bf, nullptr, nullptr, lg,
          64, 32, 65536, 65536, 64, 0, aC, aC, cL2, Z, QSCALE, 0);
      softmax_kernel<1><<<2048, 256, 0, stream>>>(lg, 131072);     // rows of 64
      BOff aP2{4096, 0, 0, 0}, bV2{2048, 0, 0, 0}, cO2{256, 3, 7, 32};
      mgemm<64,32,2,2,2,0,true><<<dim3(1, 1, 2048), 256, 0, stream>>>(
          lg, nullptr, vt_bf, nullptr, nullptr, o_bf,
          32, 64, 64, 64, 65536, 0, aP2, bV2, cO2, Z, 1.f, 0);
    }
    mgemm<128,128,2,2,1,0,false><<<gproj, 256, 0, stream>>>(
        o_bf, g_bf, wT + (18 + i) * 65536, bo2 + (size_t)i * E_, msa, msa,
        256, 256, 256, 256, 256, 256, Z, Z, Z, Z, 1.f, 0);
  }

  // final: single = msa[0] @ W_single + b_single   [256,384]
  mgemm<128,128,2,2,2,0,false><<<dim3(3, 2), 256, 0, stream>>>(
      msa, nullptr, wsT, b_single, nullptr, out,
      384, 256, 256, 256, 384, 0, Z, Z, Z, Z, 1.f, 0);
}

// Round 10
// 1086.755 us; speedup vs baseline: 1.8778x; 1.0560x over previous
//
#include <hip/hip_runtime.h>
#include <hip/hip_bf16.h>
#include <math.h>

// Problem constants
#define S_ 64
#define R_ 256
#define E_ 256
#define P_ 128
#define H_ 8
#define C_ 32
#define NB_ 2
#define SGL_ 384
#define HC_ 256                 // H_*C_
#define SRE (S_ * R_ * E_)      // 4194304

static constexpr float QSCALE = 0.17677669529663687f;  // 1/sqrt(C_)

typedef __attribute__((ext_vector_type(8))) short short8;   // 8 bf16 (4 VGPRs)
typedef __attribute__((ext_vector_type(4))) short short4v;  // 4 bf16
typedef __attribute__((ext_vector_type(4))) float f32x4;

// bf16 <-> f32 bit helpers (round-to-nearest-even)
__device__ __forceinline__ float b2f(short s) {
  union { float f; unsigned u; } x; x.u = ((unsigned)(unsigned short)s) << 16; return x.f;
}
__device__ __forceinline__ short f2b(float f) {
  union { float f; unsigned u; } x; x.f = f;
  unsigned r = x.u + 0x7fff + ((x.u >> 16) & 1);
  return (short)(r >> 16);
}

// ---------------------------------------------------------------- reductions
__device__ __forceinline__ float wave_sum(float x) {
#pragma unroll
  for (int off = 32; off >= 1; off >>= 1) x += __shfl_xor(x, off);
  return x;
}

// ---------------------------------------------------------------- LayerNorm 256 -> bf16
__global__ __launch_bounds__(256) void ln256_kernel(
    const float* __restrict__ x, const float* __restrict__ sc,
    const float* __restrict__ bi, short* __restrict__ out, int nrows) {
  int lane = threadIdx.x & 63, wv = threadIdx.x >> 6;
  float4 s4 = *(const float4*)(sc + lane * 4);
  float4 b4 = *(const float4*)(bi + lane * 4);
  for (int row = blockIdx.x * 4 + wv; row < nrows; row += gridDim.x * 4) {
    float4 v = *(const float4*)(x + (size_t)row * 256 + lane * 4);
    float mu = wave_sum(v.x + v.y + v.z + v.w) * (1.0f / 256.0f);
    float dx = v.x - mu, dy = v.y - mu, dz = v.z - mu, dw = v.w - mu;
    float var = wave_sum(dx * dx + dy * dy + dz * dz + dw * dw) * (1.0f / 256.0f);
    float inv = rsqrtf(var + 1e-5f);
    short4v o;
    o[0] = f2b(s4.x * dx * inv + b4.x);
    o[1] = f2b(s4.y * dy * inv + b4.y);
    o[2] = f2b(s4.z * dz * inv + b4.z);
    o[3] = f2b(s4.w * dw * inv + b4.w);
    *(short4v*)(out + (size_t)row * 256 + lane * 4) = o;
  }
}

// ---------------------------------------------------------------- pair row stats (mu, rsqrt(var))
__global__ __launch_bounds__(256) void pairstats_kernel(
    const float* __restrict__ pair, float2* __restrict__ st) {
  int lane = threadIdx.x & 63, wv = threadIdx.x >> 6;
  for (int row = blockIdx.x * 4 + wv; row < R_ * R_; row += gridDim.x * 4) {
    float2 v = *(const float2*)(pair + (size_t)row * P_ + lane * 2);
    float mu = wave_sum(v.x + v.y) * (1.0f / 128.0f);
    float dx = v.x - mu, dy = v.y - mu;
    float var = wave_sum(dx * dx + dy * dy) * (1.0f / 128.0f);
    float2 o; o.x = mu; o.y = rsqrtf(var + 1e-5f);
    if (lane == 0) st[row] = o;
  }
}

// ---------------------------------------------------------------- pair-bias weight prep
// wp[16][128] bf16 = sc[e]*Wb[e][h] (rows 8..15 zero); AB[h]=sum sc*Wb, AB[16+h]=sum bi*Wb
__global__ __launch_bounds__(128) void pb_prep_kernel(
    const float* __restrict__ sc, const float* __restrict__ bi,
    const float* __restrict__ Wb, short* __restrict__ wp, float* __restrict__ AB) {
  int e = threadIdx.x;
  float s = sc[e], b = bi[e];
  __shared__ float red[2];
  int lane = e & 63, wv = e >> 6;
#pragma unroll
  for (int h = 0; h < H_; ++h) {
    float w = Wb[e * H_ + h];
    wp[h * 128 + e] = f2b(s * w);
    float pa = wave_sum(s * w);
    if (lane == 0) red[wv] = pa;
    __syncthreads();
    if (e == 0) AB[h] = red[0] + red[1];
    __syncthreads();
    float pb = wave_sum(b * w);
    if (lane == 0) red[wv] = pb;
    __syncthreads();
    if (e == 0) AB[16 + h] = red[0] + red[1];
    __syncthreads();
  }
#pragma unroll
  for (int h = H_; h < 16; ++h) wp[h * 128 + e] = 0;
}

// ---------------------------------------------------------------- weight transpose+cvt
__global__ __launch_bounds__(256) void wt_kernel(
    const float* w0, const float* w1, const float* w2, const float* w3, const float* w4,
    const float* w5, const float* w6, const float* w7, const float* w8, const float* w9,
    short* __restrict__ wT) {
  __shared__ float t_[64][65];
  int mi = blockIdx.z;
  const float* srcs[10] = {w0, w1, w2, w3, w4, w5, w6, w7, w8, w9};
  const float* src = srcs[mi >> 1] + (mi & 1) * 65536;
  int kb = (blockIdx.x & 3) * 64, nb = (blockIdx.x >> 2) * 64;
  int tx = threadIdx.x & 63, ty = threadIdx.x >> 6;
#pragma unroll
  for (int i = 0; i < 16; ++i) {
    int k = i * 4 + ty;
    t_[k][tx] = src[(kb + k) * 256 + nb + tx];
  }
  __syncthreads();
#pragma unroll
  for (int i = 0; i < 16; ++i) {
    int n = i * 4 + ty;
    wT[(size_t)mi * 65536 + (nb + n) * 256 + kb + tx] = f2b(t_[tx][n]);
  }
}
// W_single [256,384] -> wsT[384][256]
__global__ __launch_bounds__(256) void wst_kernel(const float* __restrict__ w, short* __restrict__ o) {
  __shared__ float t_[64][65];
  int kb = (blockIdx.x & 3) * 64, nb = (blockIdx.x >> 2) * 64;
  int tx = threadIdx.x & 63, ty = threadIdx.x >> 6;
#pragma unroll
  for (int i = 0; i < 16; ++i) {
    int k = i * 4 + ty;
    t_[k][tx] = w[(kb + k) * SGL_ + nb + tx];
  }
  __syncthreads();
#pragma unroll
  for (int i = 0; i < 16; ++i) {
    int n = i * 4 + ty;
    o[(nb + n) * 256 + kb + tx] = f2b(t_[tx][n]);
  }
}

// ---------------------------------------------------------------- logits row stats
// Writes {rowmax, 1/sum(exp(v-max))} per row; PV applies exp on the fly.
template <int VPL>
__global__ __launch_bounds__(256) void rowstats_kernel(
    const float* __restrict__ x, float2* __restrict__ st, int nrows) {
  int wv = threadIdx.x >> 6, lane = threadIdx.x & 63;
  for (int row = blockIdx.x * 4 + wv; row < nrows; row += gridDim.x * 4) {
    const float* p = x + (size_t)row * (VPL * 64);
    float v[VPL];
    if constexpr (VPL == 4) {
      float4 t = *(const float4*)(p + lane * 4);
      v[0] = t.x; v[1] = t.y; v[2] = t.z; v[3] = t.w;
    } else {
      v[0] = p[lane];
    }
    float m = v[0];
#pragma unroll
    for (int i = 1; i < VPL; ++i) m = fmaxf(m, v[i]);
#pragma unroll
    for (int off = 32; off >= 1; off >>= 1) m = fmaxf(m, __shfl_xor(m, off));
    float s = 0.f;
#pragma unroll
    for (int i = 0; i < VPL; ++i) s += __expf(v[i] - m);
    s = wave_sum(s);
    float2 o; o.x = m; o.y = 1.0f / s;
    if (lane == 0) st[row] = o;
  }
}

// ---------------------------------------------------------------- batched MFMA GEMM
// AMODE: 0 bf16; 1 bf16*bf16 gated; 2 f32->bf16 cvt; 3 f32 logits + row stats -> exp-normalized bf16
//   (AMODE3: A2v = float2 row stats, row index = z*ldRes + bm + row)
// EPI: 0 standard (scale/bias/res/sig); 1 pair-bias (v = acc*inv - mu*inv*AB[col] + AB[16+col],
//   stats from A2v at row index; biasN = AB)
// CMODE: 0 row*ldC+col; 1 [S][H][C][R]; 2 [R][H][C][S]; 3 bias [col][row] (col<8 only)
struct BOff { long long hi; int sh; int msk; int lo; };
__device__ __forceinline__ long long boff(const BOff& o, int z) {
  return (long long)(z >> o.sh) * o.hi + (long long)(z & o.msk) * o.lo;
}

template <int BM, int BN, int WR, int WC, int AMODE, int CMODE, bool OBF, int EPI>
__global__ __launch_bounds__(256) void mgemm(
    const void* __restrict__ Av, const void* __restrict__ A2v,
    const short* __restrict__ Bt,
    const float* __restrict__ biasN, const float* resv,
    void* Cv,
    int N, int K, int ldA, int ldB, int ldC, int ldRes,
    BOff ao, BOff bo_, BOff co, BOff ro, float scale, int do_sig) {
  constexpr int WM = BM / WR, WN = BN / WC, FM = WM / 16, FN = WN / 16;
  __shared__ short As[BM][40];  // BK=32 + 8 pad (80B row stride, 16B aligned)
  __shared__ short Bs[BN][40];
  const int tid = threadIdx.x;
  const int lane = tid & 63, wave = tid >> 6;
  const int wr = wave / WC, wc = wave % WC;
  const int z = blockIdx.z;
  const int bm = blockIdx.y * BM, bn = blockIdx.x * BN;
  const long long aO = boff(ao, z), bO = boff(bo_, z), cO = boff(co, z);
  const long long rO = resv ? boff(ro, z) : 0;
  const int r16 = lane & 15, kg8 = (lane >> 4) * 8;

  f32x4 acc[FM][FN] = {};

  for (int k0 = 0; k0 < K; k0 += 32) {
    // stage A tile [BM][32]
#pragma unroll
    for (int c = tid; c < BM * 4; c += 256) {
      int row = c >> 2, k8 = (c & 3) * 8;
      long long gi = aO + (long long)(bm + row) * ldA + k0 + k8;
      short8 val;
      if constexpr (AMODE == 0) {
        val = *(const short8*)((const short*)Av + gi);
      } else if constexpr (AMODE == 1) {
        short8 x = *(const short8*)((const short*)Av + gi);
        short8 y = *(const short8*)((const short*)A2v + gi);
#pragma unroll
        for (int j = 0; j < 8; ++j) val[j] = f2b(b2f(x[j]) * b2f(y[j]));
      } else if constexpr (AMODE == 2) {
        const float* pf = (const float*)Av + gi;
        float4 f0 = *(const float4*)pf, f1 = *(const float4*)(pf + 4);
        val[0] = f2b(f0.x); val[1] = f2b(f0.y); val[2] = f2b(f0.z); val[3] = f2b(f0.w);
        val[4] = f2b(f1.x); val[5] = f2b(f1.y); val[6] = f2b(f1.z); val[7] = f2b(f1.w);
      } else {  // AMODE == 3: exp-normalize logits on the fly
        const float* pf = (const float*)Av + gi;
        float2 stv = ((const float2*)A2v)[(long long)z * ldRes + bm + row];
        float4 f0 = *(const float4*)pf, f1 = *(const float4*)(pf + 4);
        val[0] = f2b(__expf(f0.x - stv.x) * stv.y);
        val[1] = f2b(__expf(f0.y - stv.x) * stv.y);
        val[2] = f2b(__expf(f0.z - stv.x) * stv.y);
        val[3] = f2b(__expf(f0.w - stv.x) * stv.y);
        val[4] = f2b(__expf(f1.x - stv.x) * stv.y);
        val[5] = f2b(__expf(f1.y - stv.x) * stv.y);
        val[6] = f2b(__expf(f1.z - stv.x) * stv.y);
        val[7] = f2b(__expf(f1.w - stv.x) * stv.y);
      }
      *(short8*)&As[row][k8] = val;
    }
    // stage B tile [BN][32]
#pragma unroll
    for (int c = tid; c < BN * 4; c += 256) {
      int row = c >> 2, k8 = (c & 3) * 8;
      *(short8*)&Bs[row][k8] =
          *(const short8*)(Bt + bO + (long long)(bn + row) * ldB + k0 + k8);
    }
    __syncthreads();
    short8 af[FM], bfr[FN];
#pragma unroll
    for (int f = 0; f < FM; ++f) af[f] = *(const short8*)&As[wr * WM + f * 16 + r16][kg8];
#pragma unroll
    for (int f = 0; f < FN; ++f) bfr[f] = *(const short8*)&Bs[wc * WN + f * 16 + r16][kg8];
#pragma unroll
    for (int i = 0; i < FM; ++i)
#pragma unroll
      for (int j = 0; j < FN; ++j)
        acc[i][j] = __builtin_amdgcn_mfma_f32_16x16x32_bf16(af[i], bfr[j], acc[i][j], 0, 0, 0);
    __syncthreads();
  }

  // epilogue: D col = lane&15, row = (lane>>4)*4 + r   [m89-verified]
#pragma unroll
  for (int i = 0; i < FM; ++i) {
#pragma unroll
    for (int j = 0; j < FN; ++j) {
      int col = bn + wc * WN + j * 16 + r16;
      float bN = 0.f, eA = 0.f, eB = 0.f;
      if constexpr (EPI == 1) {
        eA = biasN[col]; eB = biasN[16 + col];
      } else {
        bN = biasN ? biasN[col] : 0.0f;
      }
#pragma unroll
      for (int r = 0; r < 4; ++r) {
        int row = bm + wr * WM + i * 16 + (lane >> 4) * 4 + r;
        float v;
        if constexpr (EPI == 1) {
          float2 st = ((const float2*)A2v)[(long long)z * ldRes + row];
          v = acc[i][j][r] * st.y - st.x * st.y * eA + eB;
        } else {
          v = acc[i][j][r] * scale + bN;
          if (resv) v += resv[rO + (long long)row * ldRes + col];
          if (do_sig) v = 1.0f / (1.0f + __expf(-v));
        }
        long long addr;
        if constexpr (CMODE == 0)
          addr = cO + (long long)row * ldC + col;
        else if constexpr (CMODE == 1)
          addr = (((long long)(row >> 8) * H_ + (col >> 5)) * C_ + (col & 31)) * R_ + (row & 255);
        else if constexpr (CMODE == 2)
          addr = (((long long)(row & 255) * H_ + (col >> 5)) * C_ + (col & 31)) * S_ + (row >> 8);
        else
          addr = (long long)col * (R_ * R_) + row;  // CMODE 3: [h][qk], col<8
        if constexpr (CMODE == 3) {
          if (col < H_) ((float*)Cv)[addr] = v;
        } else if constexpr (OBF) {
          ((short*)Cv)[addr] = f2b(v);
        } else {
          ((float*)Cv)[addr] = v;
        }
      }
    }
  }
}

// ---------------------------------------------------------------- launch
extern "C" void kernel_launch(void* const* d_in, const int* in_sizes, int n_in,
                              void* d_out, int out_size, void* d_ws, size_t ws_size,
                              hipStream_t stream) {
  const float* msa_in    = (const float*)d_in[0];
  const float* pair      = (const float*)d_in[1];
  const float* ln_row_s  = (const float*)d_in[2];
  const float* ln_row_b  = (const float*)d_in[3];
  const float* ln_pair_s = (const float*)d_in[4];
  const float* ln_pair_b = (const float*)d_in[5];
  const float* Wq  = (const float*)d_in[6];
  const float* Wk  = (const float*)d_in[7];
  const float* Wv  = (const float*)d_in[8];
  const float* Wb  = (const float*)d_in[9];
  const float* Wg  = (const float*)d_in[10];
  const float* bg  = (const float*)d_in[11];
  const float* Wo  = (const float*)d_in[12];
  const float* bo  = (const float*)d_in[13];
  const float* ln_col_s = (const float*)d_in[14];
  const float* ln_col_b = (const float*)d_in[15];
  const float* Wq2 = (const float*)d_in[16];
  const float* Wk2 = (const float*)d_in[17];
  const float* Wv2 = (const float*)d_in[18];
  const float* Wg2 = (const float*)d_in[19];
  const float* bg2 = (const float*)d_in[20];
  const float* Wo2 = (const float*)d_in[21];
  const float* bo2 = (const float*)d_in[22];
  const float* W_single = (const float*)d_in[23];
  const float* b_single = (const float*)d_in[24];
  float* out = (float*)d_out;

  // workspace carve (~99 MB total; proven ws >= 102.8 MB from R1 layout)
  float* msa  = (float*)d_ws;                 // 4.19M f32
  short* q_bf = (short*)(msa + SRE);          // bf16 buffers, 4.19M elems each
  short* k_bf = q_bf + SRE;
  short* vt_bf = k_bf + SRE;                  // V pre-transposed for PV
  short* g_bf = vt_bf + SRE;
  short* o_bf = g_bf + SRE;
  float* biasb = (float*)(o_bf + SRE);        // [H][R][R] f32 (2.1 MB)
  float2* pbstats = (float2*)(biasb + H_ * R_ * R_);  // pair LN stats [65536] (0.5 MB)
  float2* pstats = pbstats + R_ * R_;         // logits row stats [131072] (1 MB)
  short* wp = (short*)(pstats + 131072);      // pair-bias weights [16][128] bf16
  float* AB = (float*)(wp + 16 * 128);        // [32] f32
  short* wT  = (short*)(AB + 32);             // 20 x [256][256] bf16 (B^T)
  short* wsT = wT + 20 * 65536;               // [384][256] bf16
  short* m_bf = wsT + SGL_ * E_;              // LN output (aliased w/ lg)
  float* lg  = (float*)m_bf;                  // logits chunk: 33.5 MB f32

  hipMemcpyAsync(msa, msa_in, (size_t)SRE * sizeof(float),
                 hipMemcpyDeviceToDevice, stream);
  wt_kernel<<<dim3(16, 1, 20), 256, 0, stream>>>(Wq, Wk, Wv, Wg, Wo,
                                                 Wq2, Wk2, Wv2, Wg2, Wo2, wT);
  wst_kernel<<<24, 256, 0, stream>>>(W_single, wsT);
  pairstats_kernel<<<2048, 256, 0, stream>>>(pair, pbstats);

  const int SR = S_ * R_;
  const BOff Z{0, 0, 0, 0};
  dim3 gproj(2, SR / 128);  // [16384,256] @ [256,256]

  for (int i = 0; i < NB_; ++i) {
    // ================= row attention =================
    ln256_kernel<<<2048, 256, 0, stream>>>(msa, ln_row_s + i * E_, ln_row_b + i * E_, m_bf, SR);
    mgemm<128,128,2,2,0,0,true,0><<<gproj, 256, 0, stream>>>(
        m_bf, nullptr, wT + (0 + i) * 65536, nullptr, nullptr, q_bf,
        256, 256, 256, 256, 256, 0, Z, Z, Z, Z, 1.f, 0);
    mgemm<128,128,2,2,0,0,true,0><<<gproj, 256, 0, stream>>>(
        m_bf, nullptr, wT + (2 + i) * 65536, nullptr, nullptr, k_bf,
        256, 256, 256, 256, 256, 0, Z, Z, Z, Z, 1.f, 0);
    mgemm<128,128,2,2,0,1,true,0><<<gproj, 256, 0, stream>>>(     // V -> [S][H][C][R]
        m_bf, nullptr, wT + (4 + i) * 65536, nullptr, nullptr, vt_bf,
        256, 256, 256, 256, 256, 0, Z, Z, Z, Z, 1.f, 0);
    mgemm<128,128,2,2,0,0,true,0><<<gproj, 256, 0, stream>>>(     // gate: sigmoid(.+bg)
        m_bf, nullptr, wT + (6 + i) * 65536, bg + (size_t)i * HC_, nullptr, g_bf,
        256, 256, 256, 256, 256, 0, Z, Z, Z, Z, 1.f, 1);
    // pair bias = inv*(pair@(sc.*Wb)) - inv*mu*A + B   (MFMA + algebraic LN)
    pb_prep_kernel<<<1, 128, 0, stream>>>(ln_pair_s + i * P_, ln_pair_b + i * P_,
                                          Wb + (size_t)i * P_ * H_, wp, AB);
    mgemm<128,16,4,1,2,3,false,1><<<dim3(1, 512), 256, 0, stream>>>(
        pair, pbstats, wp, AB, nullptr, biasb,
        16, 128, 128, 128, 0, 0, Z, Z, Z, Z, 1.f, 0);

    for (int c4 = 0; c4 < 4; ++c4) {             // s-chunks of 16
      long long so = (long long)c4 * 16 * 65536;
      BOff aQ{65536, 3, 7, 32};                  // z=(s_loc,h): (z>>3)*65536+(z&7)*32
      BOff cL{65536, 0, 0, 0};
      BOff rB{0, 0, 7, 65536};                   // bias slice by h
      mgemm<128,128,2,2,0,0,false,0><<<dim3(2, 2, 128), 256, 0, stream>>>(
          q_bf + so, nullptr, k_bf + so, nullptr, biasb, lg,
          256, 32, 256, 256, 256, 256, aQ, aQ, cL, rB, QSCALE, 0);   // K=32 (per-head)
      rowstats_kernel<4><<<2048, 256, 0, stream>>>(lg, pstats, 32768);
      BOff aP{65536, 0, 0, 0}, bV{8192, 0, 0, 0}, cO{65536, 3, 7, 32};
      mgemm<128,32,4,1,3,0,true,0><<<dim3(1, 2, 128), 256, 0, stream>>>(
          lg, pstats, vt_bf + so, nullptr, nullptr, o_bf + so,
          32, 256, 256, 256, 256, 256, aP, bV, cO, Z, 1.f, 0);       // ldRes=256: stats stride
    }
    mgemm<128,128,2,2,1,0,false,0><<<gproj, 256, 0, stream>>>(    // (sig(g).*o)@Wo+bo+msa
        o_bf, g_bf, wT + (8 + i) * 65536, bo + (size_t)i * E_, msa, msa,
        256, 256, 256, 256, 256, 256, Z, Z, Z, Z, 1.f, 0);

    // ================= column attention =================
    ln256_kernel<<<2048, 256, 0, stream>>>(msa, ln_col_s + i * E_, ln_col_b + i * E_, m_bf, SR);
    mgemm<128,128,2,2,0,0,true,0><<<gproj, 256, 0, stream>>>(
        m_bf, nullptr, wT + (10 + i) * 65536, nullptr, nullptr, q_bf,
        256, 256, 256, 256, 256, 0, Z, Z, Z, Z, 1.f, 0);
    mgemm<128,128,2,2,0,0,true,0><<<gproj, 256, 0, stream>>>(
        m_bf, nullptr, wT + (12 + i) * 65536, nullptr, nullptr, k_bf,
        256, 256, 256, 256, 256, 0, Z, Z, Z, Z, 1.f, 0);
    mgemm<128,128,2,2,0,2,true,0><<<gproj, 256, 0, stream>>>(     // V -> [R][H][C][S]
        m_bf, nullptr, wT + (14 + i) * 65536, nullptr, nullptr, vt_bf,
        256, 256, 256, 256, 256, 0, Z, Z, Z, Z, 1.f, 0);
    mgemm<128,128,2,2,0,0,true,0><<<gproj, 256, 0, stream>>>(
        m_bf, nullptr, wT + (16 + i) * 65536, bg2 + (size_t)i * HC_, nullptr, g_bf,
        256, 256, 256, 256, 256, 0, Z, Z, Z, Z, 1.f, 1);
    {
      BOff aC{256, 3, 7, 32};                    // z=(r,h): (z>>3)*256+(z&7)*32
      BOff cL2{4096, 0, 0, 0};
      mgemm<64,64,2,2,0,0,false,0><<<dim3(1, 1, 2048), 256, 0, stream>>>(
          q_bf, nullptr, k_bf, nullptr, nullptr, lg,
          64, 32, 65536, 65536, 64, 0, aC, aC, cL2, Z, QSCALE, 0);
      rowstats_kernel<1><<<2048, 256, 0, stream>>>(lg, pstats, 131072);
      BOff aP2{4096, 0, 0, 0}, bV2{2048, 0, 0, 0}, cO2{256, 3, 7, 32};
      mgemm<64,32,2,2,3,0,true,0><<<dim3(1, 1, 2048), 256, 0, stream>>>(
          lg, pstats, vt_bf, nullptr, nullptr, o_bf,
          32, 64, 64, 64, 65536, 64, aP2, bV2, cO2, Z, 1.f, 0);      // ldRes=64: stats stride
    }
    mgemm<128,128,2,2,1,0,false,0><<<gproj, 256, 0, stream>>>(
        o_bf, g_bf, wT + (18 + i) * 65536, bo2 + (size_t)i * E_, msa, msa,
        256, 256, 256, 256, 256, 256, Z, Z, Z, Z, 1.f, 0);
  }

  // final: single = msa[0] @ W_single + b_single   [256,384]
  mgemm<128,128,2,2,2,0,false,0><<<dim3(3, 2), 256, 0, stream>>>(
      msa, nullptr, wsT, b_single, nullptr, out,
      384, 256, 256, 256, 384, 0, Z, Z, Z, Z, 1.f, 0);
}

// Round 11
// 849.656 us; speedup vs baseline: 2.4019x; 1.2791x over previous
//
#include <hip/hip_runtime.h>
#include <hip/hip_bf16.h>
#include <math.h>

// Problem constants
#define S_ 64
#define R_ 256
#define E_ 256
#define P_ 128
#define H_ 8
#define C_ 32
#define NB_ 2
#define SGL_ 384
#define HC_ 256                 // H_*C_
#define SRE (S_ * R_ * E_)      // 4194304

static constexpr float QSCALE = 0.17677669529663687f;  // 1/sqrt(C_)

typedef __attribute__((ext_vector_type(8))) short short8;   // 8 bf16 (4 VGPRs)
typedef __attribute__((ext_vector_type(4))) short short4v;  // 4 bf16
typedef __attribute__((ext_vector_type(4))) float f32x4;

// bf16 <-> f32 bit helpers (round-to-nearest-even)
__device__ __forceinline__ float b2f(short s) {
  union { float f; unsigned u; } x; x.u = ((unsigned)(unsigned short)s) << 16; return x.f;
}
__device__ __forceinline__ short f2b(float f) {
  union { float f; unsigned u; } x; x.f = f;
  unsigned r = x.u + 0x7fff + ((x.u >> 16) & 1);
  return (short)(r >> 16);
}

// ---------------------------------------------------------------- reductions
__device__ __forceinline__ float wave_sum(float x) {
#pragma unroll
  for (int off = 32; off >= 1; off >>= 1) x += __shfl_xor(x, off);
  return x;
}

// ---------------------------------------------------------------- LayerNorm 256 -> bf16
__global__ __launch_bounds__(256) void ln256_kernel(
    const float* __restrict__ x, const float* __restrict__ sc,
    const float* __restrict__ bi, short* __restrict__ out, int nrows) {
  int lane = threadIdx.x & 63, wv = threadIdx.x >> 6;
  float4 s4 = *(const float4*)(sc + lane * 4);
  float4 b4 = *(const float4*)(bi + lane * 4);
  for (int row = blockIdx.x * 4 + wv; row < nrows; row += gridDim.x * 4) {
    float4 v = *(const float4*)(x + (size_t)row * 256 + lane * 4);
    float mu = wave_sum(v.x + v.y + v.z + v.w) * (1.0f / 256.0f);
    float dx = v.x - mu, dy = v.y - mu, dz = v.z - mu, dw = v.w - mu;
    float var = wave_sum(dx * dx + dy * dy + dz * dz + dw * dw) * (1.0f / 256.0f);
    float inv = rsqrtf(var + 1e-5f);
    short4v o;
    o[0] = f2b(s4.x * dx * inv + b4.x);
    o[1] = f2b(s4.y * dy * inv + b4.y);
    o[2] = f2b(s4.z * dz * inv + b4.z);
    o[3] = f2b(s4.w * dw * inv + b4.w);
    *(short4v*)(out + (size_t)row * 256 + lane * 4) = o;
  }
}

// ---------------------------------------------------------------- pair row stats (mu, rsqrt(var))
__global__ __launch_bounds__(256) void pairstats_kernel(
    const float* __restrict__ pair, float2* __restrict__ st) {
  int lane = threadIdx.x & 63, wv = threadIdx.x >> 6;
  for (int row = blockIdx.x * 4 + wv; row < R_ * R_; row += gridDim.x * 4) {
    float2 v = *(const float2*)(pair + (size_t)row * P_ + lane * 2);
    float mu = wave_sum(v.x + v.y) * (1.0f / 128.0f);
    float dx = v.x - mu, dy = v.y - mu;
    float var = wave_sum(dx * dx + dy * dy) * (1.0f / 128.0f);
    float2 o; o.x = mu; o.y = rsqrtf(var + 1e-5f);
    if (lane == 0) st[row] = o;
  }
}

// ---------------------------------------------------------------- pair-bias weight prep
// wp[16][128] bf16 = sc[e]*Wb[e][h] (rows 8..15 zero); AB[h]=sum sc*Wb, AB[16+h]=sum bi*Wb
__global__ __launch_bounds__(128) void pb_prep_kernel(
    const float* __restrict__ sc, const float* __restrict__ bi,
    const float* __restrict__ Wb, short* __restrict__ wp, float* __restrict__ AB) {
  int e = threadIdx.x;
  float s = sc[e], b = bi[e];
  __shared__ float red[2];
  int lane = e & 63, wv = e >> 6;
#pragma unroll
  for (int h = 0; h < H_; ++h) {
    float w = Wb[e * H_ + h];
    wp[h * 128 + e] = f2b(s * w);
    float pa = wave_sum(s * w);
    if (lane == 0) red[wv] = pa;
    __syncthreads();
    if (e == 0) AB[h] = red[0] + red[1];
    __syncthreads();
    float pb = wave_sum(b * w);
    if (lane == 0) red[wv] = pb;
    __syncthreads();
    if (e == 0) AB[16 + h] = red[0] + red[1];
    __syncthreads();
  }
#pragma unroll
  for (int h = H_; h < 16; ++h) wp[h * 128 + e] = 0;
}

// ---------------------------------------------------------------- weight transpose+cvt
__global__ __launch_bounds__(256) void wt_kernel(
    const float* w0, const float* w1, const float* w2, const float* w3, const float* w4,
    const float* w5, const float* w6, const float* w7, const float* w8, const float* w9,
    short* __restrict__ wT) {
  __shared__ float t_[64][65];
  int mi = blockIdx.z;
  const float* srcs[10] = {w0, w1, w2, w3, w4, w5, w6, w7, w8, w9};
  const float* src = srcs[mi >> 1] + (mi & 1) * 65536;
  int kb = (blockIdx.x & 3) * 64, nb = (blockIdx.x >> 2) * 64;
  int tx = threadIdx.x & 63, ty = threadIdx.x >> 6;
#pragma unroll
  for (int i = 0; i < 16; ++i) {
    int k = i * 4 + ty;
    t_[k][tx] = src[(kb + k) * 256 + nb + tx];
  }
  __syncthreads();
#pragma unroll
  for (int i = 0; i < 16; ++i) {
    int n = i * 4 + ty;
    wT[(size_t)mi * 65536 + (nb + n) * 256 + kb + tx] = f2b(t_[tx][n]);
  }
}
// W_single [256,384] -> wsT[384][256]
__global__ __launch_bounds__(256) void wst_kernel(const float* __restrict__ w, short* __restrict__ o) {
  __shared__ float t_[64][65];
  int kb = (blockIdx.x & 3) * 64, nb = (blockIdx.x >> 2) * 64;
  int tx = threadIdx.x & 63, ty = threadIdx.x >> 6;
#pragma unroll
  for (int i = 0; i < 16; ++i) {
    int k = i * 4 + ty;
    t_[k][tx] = w[(kb + k) * SGL_ + nb + tx];
  }
  __syncthreads();
#pragma unroll
  for (int i = 0; i < 16; ++i) {
    int n = i * 4 + ty;
    o[(nb + n) * 256 + kb + tx] = f2b(t_[tx][n]);
  }
}

// ---------------------------------------------------------------- logits row stats
// Writes {rowmax, 1/sum(exp(v-max))} per row; PV applies exp on the fly.
template <int VPL>
__global__ __launch_bounds__(256) void rowstats_kernel(
    const float* __restrict__ x, float2* __restrict__ st, int nrows) {
  int wv = threadIdx.x >> 6, lane = threadIdx.x & 63;
  for (int row = blockIdx.x * 4 + wv; row < nrows; row += gridDim.x * 4) {
    const float* p = x + (size_t)row * (VPL * 64);
    float v[VPL];
    if constexpr (VPL == 4) {
      float4 t = *(const float4*)(p + lane * 4);
      v[0] = t.x; v[1] = t.y; v[2] = t.z; v[3] = t.w;
    } else {
      v[0] = p[lane];
    }
    float m = v[0];
#pragma unroll
    for (int i = 1; i < VPL; ++i) m = fmaxf(m, v[i]);
#pragma unroll
    for (int off = 32; off >= 1; off >>= 1) m = fmaxf(m, __shfl_xor(m, off));
    float s = 0.f;
#pragma unroll
    for (int i = 0; i < VPL; ++i) s += __expf(v[i] - m);
    s = wave_sum(s);
    float2 o; o.x = m; o.y = 1.0f / s;
    if (lane == 0) st[row] = o;
  }
}

// ---------------------------------------------------------------- batched MFMA GEMM
// AMODE: 0 bf16; 1 bf16*bf16 gated; 2 f32->bf16 cvt; 3 f32 logits + stats -> exp-normalized bf16
//   (AMODE3: A2v = float2 row stats, row index = z*ldRes + bm + row)
// EPI: 0 standard; 1 pair-bias (v = acc*inv - mu*inv*AB[col] + AB[16+col]; biasN = AB)
// CMODE: 0 row*ldC+col; 1 [S][H][C][R]; 2 [R][H][C][S]; 3 bias [col][row] (col<8 only)
// PROJ: 0 off; 1/2 fused QKVG projection (z: 0->q, 1->k, 2->v-transposed (1=row,2=col),
//   3->sigmoid gate; Cv = q_bf base, buffers SRE apart; biasN = bg)
struct BOff { long long hi; int sh; int msk; int lo; };
__device__ __forceinline__ long long boff(const BOff& o, int z) {
  return (long long)(z >> o.sh) * o.hi + (long long)(z & o.msk) * o.lo;
}

template <int BM, int BN, int WR, int WC, int AMODE, int CMODE, bool OBF, int EPI, int PROJ = 0>
__global__ __launch_bounds__(256) void mgemm(
    const void* __restrict__ Av, const void* __restrict__ A2v,
    const short* __restrict__ Bt,
    const float* __restrict__ biasN, const float* resv,
    void* Cv,
    int N, int K, int ldA, int ldB, int ldC, int ldRes,
    BOff ao, BOff bo_, BOff co, BOff ro, float scale, int do_sig) {
  constexpr int WM = BM / WR, WN = BN / WC, FM = WM / 16, FN = WN / 16;
  __shared__ short As[BM][40];  // BK=32 + 8 pad (80B row stride, 16B aligned)
  __shared__ short Bs[BN][40];
  const int tid = threadIdx.x;
  const int lane = tid & 63, wave = tid >> 6;
  const int wr = wave / WC, wc = wave % WC;
  const int z = blockIdx.z;
  const int bm = blockIdx.y * BM, bn = blockIdx.x * BN;
  const long long aO = boff(ao, z), bO = boff(bo_, z), cO = boff(co, z);
  const long long rO = resv ? boff(ro, z) : 0;
  const int r16 = lane & 15, kg8 = (lane >> 4) * 8;

  f32x4 acc[FM][FN] = {};

  for (int k0 = 0; k0 < K; k0 += 32) {
    // stage A tile [BM][32]
#pragma unroll
    for (int c = tid; c < BM * 4; c += 256) {
      int row = c >> 2, k8 = (c & 3) * 8;
      long long gi = aO + (long long)(bm + row) * ldA + k0 + k8;
      short8 val;
      if constexpr (AMODE == 0) {
        val = *(const short8*)((const short*)Av + gi);
      } else if constexpr (AMODE == 1) {
        short8 x = *(const short8*)((const short*)Av + gi);
        short8 y = *(const short8*)((const short*)A2v + gi);
#pragma unroll
        for (int j = 0; j < 8; ++j) val[j] = f2b(b2f(x[j]) * b2f(y[j]));
      } else if constexpr (AMODE == 2) {
        const float* pf = (const float*)Av + gi;
        float4 f0 = *(const float4*)pf, f1 = *(const float4*)(pf + 4);
        val[0] = f2b(f0.x); val[1] = f2b(f0.y); val[2] = f2b(f0.z); val[3] = f2b(f0.w);
        val[4] = f2b(f1.x); val[5] = f2b(f1.y); val[6] = f2b(f1.z); val[7] = f2b(f1.w);
      } else {  // AMODE == 3: exp-normalize logits on the fly
        const float* pf = (const float*)Av + gi;
        float2 stv = ((const float2*)A2v)[(long long)z * ldRes + bm + row];
        float4 f0 = *(const float4*)pf, f1 = *(const float4*)(pf + 4);
        val[0] = f2b(__expf(f0.x - stv.x) * stv.y);
        val[1] = f2b(__expf(f0.y - stv.x) * stv.y);
        val[2] = f2b(__expf(f0.z - stv.x) * stv.y);
        val[3] = f2b(__expf(f0.w - stv.x) * stv.y);
        val[4] = f2b(__expf(f1.x - stv.x) * stv.y);
        val[5] = f2b(__expf(f1.y - stv.x) * stv.y);
        val[6] = f2b(__expf(f1.z - stv.x) * stv.y);
        val[7] = f2b(__expf(f1.w - stv.x) * stv.y);
      }
      *(short8*)&As[row][k8] = val;
    }
    // stage B tile [BN][32]
#pragma unroll
    for (int c = tid; c < BN * 4; c += 256) {
      int row = c >> 2, k8 = (c & 3) * 8;
      *(short8*)&Bs[row][k8] =
          *(const short8*)(Bt + bO + (long long)(bn + row) * ldB + k0 + k8);
    }
    __syncthreads();
    short8 af[FM], bfr[FN];
#pragma unroll
    for (int f = 0; f < FM; ++f) af[f] = *(const short8*)&As[wr * WM + f * 16 + r16][kg8];
#pragma unroll
    for (int f = 0; f < FN; ++f) bfr[f] = *(const short8*)&Bs[wc * WN + f * 16 + r16][kg8];
#pragma unroll
    for (int i = 0; i < FM; ++i)
#pragma unroll
      for (int j = 0; j < FN; ++j)
        acc[i][j] = __builtin_amdgcn_mfma_f32_16x16x32_bf16(af[i], bfr[j], acc[i][j], 0, 0, 0);
    __syncthreads();
  }

  // epilogue: D col = lane&15, row = (lane>>4)*4 + r   [m89-verified]
#pragma unroll
  for (int i = 0; i < FM; ++i) {
#pragma unroll
    for (int j = 0; j < FN; ++j) {
      int col = bn + wc * WN + j * 16 + r16;
      float bN = 0.f, eA = 0.f, eB = 0.f;
      if constexpr (PROJ > 0) {
        if (z == 3) bN = biasN[col];
      } else if constexpr (EPI == 1) {
        eA = biasN[col]; eB = biasN[16 + col];
      } else {
        bN = biasN ? biasN[col] : 0.0f;
      }
#pragma unroll
      for (int r = 0; r < 4; ++r) {
        int row = bm + wr * WM + i * 16 + (lane >> 4) * 4 + r;
        if constexpr (PROJ > 0) {
          float v = acc[i][j][r];
          if (z == 3) v = 1.0f / (1.0f + __expf(-(v + bN)));
          long long addr;
          if (z == 2) {
            if constexpr (PROJ == 1)
              addr = 2LL * SRE +
                     (((long long)(row >> 8) * H_ + (col >> 5)) * C_ + (col & 31)) * R_ + (row & 255);
            else
              addr = 2LL * SRE +
                     (((long long)(row & 255) * H_ + (col >> 5)) * C_ + (col & 31)) * S_ + (row >> 8);
          } else {
            addr = (long long)z * SRE + (long long)row * 256 + col;
          }
          ((short*)Cv)[addr] = f2b(v);
        } else {
          float v;
          if constexpr (EPI == 1) {
            float2 st = ((const float2*)A2v)[(long long)z * ldRes + row];
            v = acc[i][j][r] * st.y - st.x * st.y * eA + eB;
          } else {
            v = acc[i][j][r] * scale + bN;
            if (resv) v += resv[rO + (long long)row * ldRes + col];
            if (do_sig) v = 1.0f / (1.0f + __expf(-v));
          }
          long long addr;
          if constexpr (CMODE == 0)
            addr = cO + (long long)row * ldC + col;
          else if constexpr (CMODE == 1)
            addr = (((long long)(row >> 8) * H_ + (col >> 5)) * C_ + (col & 31)) * R_ + (row & 255);
          else if constexpr (CMODE == 2)
            addr = (((long long)(row & 255) * H_ + (col >> 5)) * C_ + (col & 31)) * S_ + (row >> 8);
          else
            addr = (long long)col * (R_ * R_) + row;  // CMODE 3: [h][qk], col<8
          if constexpr (CMODE == 3) {
            if (col < H_) ((float*)Cv)[addr] = v;
          } else if constexpr (OBF) {
            ((short*)Cv)[addr] = f2b(v);
          } else {
            ((float*)Cv)[addr] = v;
          }
        }
      }
    }
  }
}

// ---------------------------------------------------------------- launch
extern "C" void kernel_launch(void* const* d_in, const int* in_sizes, int n_in,
                              void* d_out, int out_size, void* d_ws, size_t ws_size,
                              hipStream_t stream) {
  const float* msa_in    = (const float*)d_in[0];
  const float* pair      = (const float*)d_in[1];
  const float* ln_row_s  = (const float*)d_in[2];
  const float* ln_row_b  = (const float*)d_in[3];
  const float* ln_pair_s = (const float*)d_in[4];
  const float* ln_pair_b = (const float*)d_in[5];
  const float* Wq  = (const float*)d_in[6];
  const float* Wk  = (const float*)d_in[7];
  const float* Wv  = (const float*)d_in[8];
  const float* Wb  = (const float*)d_in[9];
  const float* Wg  = (const float*)d_in[10];
  const float* bg  = (const float*)d_in[11];
  const float* Wo  = (const float*)d_in[12];
  const float* bo  = (const float*)d_in[13];
  const float* ln_col_s = (const float*)d_in[14];
  const float* ln_col_b = (const float*)d_in[15];
  const float* Wq2 = (const float*)d_in[16];
  const float* Wk2 = (const float*)d_in[17];
  const float* Wv2 = (const float*)d_in[18];
  const float* Wg2 = (const float*)d_in[19];
  const float* bg2 = (const float*)d_in[20];
  const float* Wo2 = (const float*)d_in[21];
  const float* bo2 = (const float*)d_in[22];
  const float* W_single = (const float*)d_in[23];
  const float* b_single = (const float*)d_in[24];
  float* out = (float*)d_out;

  // workspace carve; lg sized by ws_size (full row-attn logits = 134 MB when ws allows)
  float* msa  = (float*)d_ws;                 // 4.19M f32
  short* q_bf = (short*)(msa + SRE);          // q,k,vt,g contiguous SRE-sized (PROJ relies on it)
  short* k_bf = q_bf + SRE;
  short* vt_bf = k_bf + SRE;
  short* g_bf = vt_bf + SRE;
  short* o_bf = g_bf + SRE;
  float* biasb = (float*)(o_bf + SRE);        // [H][R][R] f32 (2.1 MB)
  float2* pbstats = (float2*)(biasb + H_ * R_ * R_);  // pair LN stats (0.5 MB)
  float2* pstats = pbstats + R_ * R_;         // logits row stats [131072] (1 MB)
  short* wp = (short*)(pstats + 131072);      // pair-bias weights [16][128] bf16
  float* AB = (float*)(wp + 16 * 128);        // [32] f32
  short* wT  = (short*)(AB + 32);             // 20 x [256][256] bf16 (B^T)
  short* wsT = wT + 20 * 65536;               // [384][256] bf16
  short* m_bf = wsT + SGL_ * E_;              // LN output (aliases lg head; dead before QK)
  float* lg  = (float*)m_bf;                  // logits: 33.5 MB (chunked) / 134 MB (full)

  // ws_size gate: full path needs ~200 MB (lg 134 MB); fallback = proven 4-chunk (99 MB)
  const int nch = (ws_size >= (size_t)210 * 1024 * 1024) ? 1 : 4;
  const int zper = 512 / nch;

  hipMemcpyAsync(msa, msa_in, (size_t)SRE * sizeof(float),
                 hipMemcpyDeviceToDevice, stream);
  wt_kernel<<<dim3(16, 1, 20), 256, 0, stream>>>(Wq, Wk, Wv, Wg, Wo,
                                                 Wq2, Wk2, Wv2, Wg2, Wo2, wT);
  wst_kernel<<<24, 256, 0, stream>>>(W_single, wsT);
  pairstats_kernel<<<2048, 256, 0, stream>>>(pair, pbstats);

  const int SR = S_ * R_;
  const BOff Z{0, 0, 0, 0};
  const BOff bW{131072, 0, 0, 0};  // weight-slot stride for PROJ (2 mats of 65536)
  dim3 gproj(2, SR / 128);

  for (int i = 0; i < NB_; ++i) {
    // ================= row attention =================
    ln256_kernel<<<2048, 256, 0, stream>>>(msa, ln_row_s + i * E_, ln_row_b + i * E_, m_bf, SR);
    // fused Q/K/V/G projection: z=0 q, 1 k, 2 v->[S][H][C][R], 3 sigmoid gate
    mgemm<128,128,2,2,0,0,true,0,1><<<dim3(2, SR / 128, 4), 256, 0, stream>>>(
        m_bf, nullptr, wT + i * 65536, bg + (size_t)i * HC_, nullptr, q_bf,
        256, 256, 256, 256, 256, 0, Z, bW, Z, Z, 1.f, 0);
    // pair bias = inv*(pair@(sc.*Wb)) - inv*mu*A + B   (MFMA + algebraic LN)
    pb_prep_kernel<<<1, 128, 0, stream>>>(ln_pair_s + i * P_, ln_pair_b + i * P_,
                                          Wb + (size_t)i * P_ * H_, wp, AB);
    mgemm<128,16,4,1,2,3,false,1><<<dim3(1, 512), 256, 0, stream>>>(
        pair, pbstats, wp, AB, nullptr, biasb,
        16, 128, 128, 128, 0, 0, Z, Z, Z, Z, 1.f, 0);

    for (int c4 = 0; c4 < nch; ++c4) {           // s-chunks (1 chunk when ws allows)
      long long so = (long long)c4 * (zper / 8) * 65536;
      BOff aQ{65536, 3, 7, 32};                  // z=(s_loc,h): (z>>3)*65536+(z&7)*32
      BOff cL{65536, 0, 0, 0};
      BOff rB{0, 0, 7, 65536};                   // bias slice by h
      mgemm<128,128,2,2,0,0,false,0><<<dim3(2, 2, zper), 256, 0, stream>>>(
          q_bf + so, nullptr, k_bf + so, nullptr, biasb, lg,
          256, 32, 256, 256, 256, 256, aQ, aQ, cL, rB, QSCALE, 0);   // K=32 (per-head)
      rowstats_kernel<4><<<2048, 256, 0, stream>>>(lg, pstats, zper * 256);
      BOff aP{65536, 0, 0, 0}, bV{8192, 0, 0, 0}, cO{65536, 3, 7, 32};
      mgemm<128,32,4,1,3,0,true,0><<<dim3(1, 2, zper), 256, 0, stream>>>(
          lg, pstats, vt_bf + so, nullptr, nullptr, o_bf + so,
          32, 256, 256, 256, 256, 256, aP, bV, cO, Z, 1.f, 0);       // ldRes=256: stats stride
    }
    mgemm<128,128,2,2,1,0,false,0><<<gproj, 256, 0, stream>>>(    // (sig(g).*o)@Wo+bo+msa
        o_bf, g_bf, wT + (8 + i) * 65536, bo + (size_t)i * E_, msa, msa,
        256, 256, 256, 256, 256, 256, Z, Z, Z, Z, 1.f, 0);

    // ================= column attention =================
    ln256_kernel<<<2048, 256, 0, stream>>>(msa, ln_col_s + i * E_, ln_col_b + i * E_, m_bf, SR);
    mgemm<128,128,2,2,0,0,true,0,2><<<dim3(2, SR / 128, 4), 256, 0, stream>>>(
        m_bf, nullptr, wT + (10 + i) * 65536, bg2 + (size_t)i * HC_, nullptr, q_bf,
        256, 256, 256, 256, 256, 0, Z, bW, Z, Z, 1.f, 0);
    {
      BOff aC{256, 3, 7, 32};                    // z=(r,h): (z>>3)*256+(z&7)*32
      BOff cL2{4096, 0, 0, 0};
      mgemm<64,64,2,2,0,0,false,0><<<dim3(1, 1, 2048), 256, 0, stream>>>(
          q_bf, nullptr, k_bf, nullptr, nullptr, lg,
          64, 32, 65536, 65536, 64, 0, aC, aC, cL2, Z, QSCALE, 0);
      rowstats_kernel<1><<<2048, 256, 0, stream>>>(lg, pstats, 131072);
      BOff aP2{4096, 0, 0, 0}, bV2{2048, 0, 0, 0}, cO2{256, 3, 7, 32};
      mgemm<64,32,2,2,3,0,true,0><<<dim3(1, 1, 2048), 256, 0, stream>>>(
          lg, pstats, vt_bf, nullptr, nullptr, o_bf,
          32, 64, 64, 64, 65536, 64, aP2, bV2, cO2, Z, 1.f, 0);      // ldRes=64: stats stride
    }
    mgemm<128,128,2,2,1,0,false,0><<<gproj, 256, 0, stream>>>(
        o_bf, g_bf, wT + (18 + i) * 65536, bo2 + (size_t)i * E_, msa, msa,
        256, 256, 256, 256, 256, 256, Z, Z, Z, Z, 1.f, 0);
  }

  // final: single = msa[0] @ W_single + b_single   [256,384]
  mgemm<128,128,2,2,2,0,false,0><<<dim3(3, 2), 256, 0, stream>>>(
      msa, nullptr, wsT, b_single, nullptr, out,
      384, 256, 256, 256, 384, 0, Z, Z, Z, Z, 1.f, 0);
}

// Round 12
// 832.137 us; speedup vs baseline: 2.4524x; 1.0211x over previous
//
#include <hip/hip_runtime.h>
#include <hip/hip_bf16.h>
#include <math.h>

// Problem constants
#define S_ 64
#define R_ 256
#define E_ 256
#define P_ 128
#define H_ 8
#define C_ 32
#define NB_ 2
#define SGL_ 384
#define HC_ 256                 // H_*C_
#define SRE (S_ * R_ * E_)      // 4194304

static constexpr float QSCALE = 0.17677669529663687f;  // 1/sqrt(C_)

typedef __attribute__((ext_vector_type(8))) short short8;   // 8 bf16 (4 VGPRs)
typedef __attribute__((ext_vector_type(4))) short short4v;  // 4 bf16
typedef __attribute__((ext_vector_type(4))) float f32x4;

// bf16 <-> f32 bit helpers (round-to-nearest-even)
__device__ __forceinline__ float b2f(short s) {
  union { float f; unsigned u; } x; x.u = ((unsigned)(unsigned short)s) << 16; return x.f;
}
__device__ __forceinline__ short f2b(float f) {
  union { float f; unsigned u; } x; x.f = f;
  unsigned r = x.u + 0x7fff + ((x.u >> 16) & 1);
  return (short)(r >> 16);
}

// ---------------------------------------------------------------- reductions
__device__ __forceinline__ float wave_sum(float x) {
#pragma unroll
  for (int off = 32; off >= 1; off >>= 1) x += __shfl_xor(x, off);
  return x;
}

// ---------------------------------------------------------------- LayerNorm 256 -> bf16
__global__ __launch_bounds__(256) void ln256_kernel(
    const float* __restrict__ x, const float* __restrict__ sc,
    const float* __restrict__ bi, short* __restrict__ out, int nrows) {
  int lane = threadIdx.x & 63, wv = threadIdx.x >> 6;
  float4 s4 = *(const float4*)(sc + lane * 4);
  float4 b4 = *(const float4*)(bi + lane * 4);
  for (int row = blockIdx.x * 4 + wv; row < nrows; row += gridDim.x * 4) {
    float4 v = *(const float4*)(x + (size_t)row * 256 + lane * 4);
    float mu = wave_sum(v.x + v.y + v.z + v.w) * (1.0f / 256.0f);
    float dx = v.x - mu, dy = v.y - mu, dz = v.z - mu, dw = v.w - mu;
    float var = wave_sum(dx * dx + dy * dy + dz * dz + dw * dw) * (1.0f / 256.0f);
    float inv = rsqrtf(var + 1e-5f);
    short4v o;
    o[0] = f2b(s4.x * dx * inv + b4.x);
    o[1] = f2b(s4.y * dy * inv + b4.y);
    o[2] = f2b(s4.z * dz * inv + b4.z);
    o[3] = f2b(s4.w * dw * inv + b4.w);
    *(short4v*)(out + (size_t)row * 256 + lane * 4) = o;
  }
}

// ---------------------------------------------------------------- pair row stats (mu, rsqrt(var))
__global__ __launch_bounds__(256) void pairstats_kernel(
    const float* __restrict__ pair, float2* __restrict__ st) {
  int lane = threadIdx.x & 63, wv = threadIdx.x >> 6;
  for (int row = blockIdx.x * 4 + wv; row < R_ * R_; row += gridDim.x * 4) {
    float2 v = *(const float2*)(pair + (size_t)row * P_ + lane * 2);
    float mu = wave_sum(v.x + v.y) * (1.0f / 128.0f);
    float dx = v.x - mu, dy = v.y - mu;
    float var = wave_sum(dx * dx + dy * dy) * (1.0f / 128.0f);
    float2 o; o.x = mu; o.y = rsqrtf(var + 1e-5f);
    if (lane == 0) st[row] = o;
  }
}

// ---------------------------------------------------------------- pair-bias weight prep
// wp[16][128] bf16 = sc[e]*Wb[e][h] (rows 8..15 zero); AB[h]=sum sc*Wb, AB[16+h]=sum bi*Wb
__global__ __launch_bounds__(128) void pb_prep_kernel(
    const float* __restrict__ sc, const float* __restrict__ bi,
    const float* __restrict__ Wb, short* __restrict__ wp, float* __restrict__ AB) {
  int e = threadIdx.x;
  float s = sc[e], b = bi[e];
  __shared__ float red[2];
  int lane = e & 63, wv = e >> 6;
#pragma unroll
  for (int h = 0; h < H_; ++h) {
    float w = Wb[e * H_ + h];
    wp[h * 128 + e] = f2b(s * w);
    float pa = wave_sum(s * w);
    if (lane == 0) red[wv] = pa;
    __syncthreads();
    if (e == 0) AB[h] = red[0] + red[1];
    __syncthreads();
    float pb = wave_sum(b * w);
    if (lane == 0) red[wv] = pb;
    __syncthreads();
    if (e == 0) AB[16 + h] = red[0] + red[1];
    __syncthreads();
  }
#pragma unroll
  for (int h = H_; h < 16; ++h) wp[h * 128 + e] = 0;
}

// ---------------------------------------------------------------- weight transpose+cvt
__global__ __launch_bounds__(256) void wt_kernel(
    const float* w0, const float* w1, const float* w2, const float* w3, const float* w4,
    const float* w5, const float* w6, const float* w7, const float* w8, const float* w9,
    short* __restrict__ wT) {
  __shared__ float t_[64][65];
  int mi = blockIdx.z;
  const float* srcs[10] = {w0, w1, w2, w3, w4, w5, w6, w7, w8, w9};
  const float* src = srcs[mi >> 1] + (mi & 1) * 65536;
  int kb = (blockIdx.x & 3) * 64, nb = (blockIdx.x >> 2) * 64;
  int tx = threadIdx.x & 63, ty = threadIdx.x >> 6;
#pragma unroll
  for (int i = 0; i < 16; ++i) {
    int k = i * 4 + ty;
    t_[k][tx] = src[(kb + k) * 256 + nb + tx];
  }
  __syncthreads();
#pragma unroll
  for (int i = 0; i < 16; ++i) {
    int n = i * 4 + ty;
    wT[(size_t)mi * 65536 + (nb + n) * 256 + kb + tx] = f2b(t_[tx][n]);
  }
}
// W_single [256,384] -> wsT[384][256]
__global__ __launch_bounds__(256) void wst_kernel(const float* __restrict__ w, short* __restrict__ o) {
  __shared__ float t_[64][65];
  int kb = (blockIdx.x & 3) * 64, nb = (blockIdx.x >> 2) * 64;
  int tx = threadIdx.x & 63, ty = threadIdx.x >> 6;
#pragma unroll
  for (int i = 0; i < 16; ++i) {
    int k = i * 4 + ty;
    t_[k][tx] = w[(kb + k) * SGL_ + nb + tx];
  }
  __syncthreads();
#pragma unroll
  for (int i = 0; i < 16; ++i) {
    int n = i * 4 + ty;
    o[(nb + n) * 256 + kb + tx] = f2b(t_[tx][n]);
  }
}

// ---------------------------------------------------------------- logits row stats (bf16 logits)
// Writes {rowmax, 1/sum(exp(v-max))} per row; PV applies exp on the fly.
template <int VPL>
__global__ __launch_bounds__(256) void rowstats_kernel(
    const short* __restrict__ x, float2* __restrict__ st, int nrows) {
  int wv = threadIdx.x >> 6, lane = threadIdx.x & 63;
  for (int row = blockIdx.x * 4 + wv; row < nrows; row += gridDim.x * 4) {
    const short* p = x + (size_t)row * (VPL * 64);
    float v[VPL];
    if constexpr (VPL == 4) {
      short4v t = *(const short4v*)(p + lane * 4);
      v[0] = b2f(t[0]); v[1] = b2f(t[1]); v[2] = b2f(t[2]); v[3] = b2f(t[3]);
    } else {
      v[0] = b2f(p[lane]);
    }
    float m = v[0];
#pragma unroll
    for (int i = 1; i < VPL; ++i) m = fmaxf(m, v[i]);
#pragma unroll
    for (int off = 32; off >= 1; off >>= 1) m = fmaxf(m, __shfl_xor(m, off));
    float s = 0.f;
#pragma unroll
    for (int i = 0; i < VPL; ++i) s += __expf(v[i] - m);
    s = wave_sum(s);
    float2 o; o.x = m; o.y = 1.0f / s;
    if (lane == 0) st[row] = o;
  }
}

// ---------------------------------------------------------------- batched MFMA GEMM
// AMODE: 0 bf16; 1 bf16*bf16 gated; 2 f32->bf16 cvt; 3 bf16 logits + stats -> exp-normalized bf16
//   (AMODE3: A2v = float2 row stats, row index = z*ldRes + bm + row)
// EPI: 0 standard; 1 pair-bias (v = acc*inv - mu*inv*AB[col] + AB[16+col]; biasN = AB)
// CMODE: 0 row*ldC+col; 1 [S][H][C][R]; 2 [R][H][C][S]; 3 bias [col][row] (col<8 only)
// PROJ: 0 off; 1/2 fused QKVG projection (z: 0->q, 1->k, 2->v-transposed (1=row,2=col),
//   3->sigmoid gate; Cv = q_bf base, buffers SRE apart; biasN = bg)
struct BOff { long long hi; int sh; int msk; int lo; };
__device__ __forceinline__ long long boff(const BOff& o, int z) {
  return (long long)(z >> o.sh) * o.hi + (long long)(z & o.msk) * o.lo;
}

template <int BM, int BN, int WR, int WC, int AMODE, int CMODE, bool OBF, int EPI, int PROJ = 0>
__global__ __launch_bounds__(256) void mgemm(
    const void* __restrict__ Av, const void* __restrict__ A2v,
    const short* __restrict__ Bt,
    const float* __restrict__ biasN, const float* resv,
    void* Cv,
    int N, int K, int ldA, int ldB, int ldC, int ldRes,
    BOff ao, BOff bo_, BOff co, BOff ro, float scale, int do_sig) {
  constexpr int WM = BM / WR, WN = BN / WC, FM = WM / 16, FN = WN / 16;
  __shared__ short As[BM][40];  // BK=32 + 8 pad (80B row stride, 16B aligned)
  __shared__ short Bs[BN][40];
  const int tid = threadIdx.x;
  const int lane = tid & 63, wave = tid >> 6;
  const int wr = wave / WC, wc = wave % WC;
  const int z = blockIdx.z;
  const int bm = blockIdx.y * BM, bn = blockIdx.x * BN;
  const long long aO = boff(ao, z), bO = boff(bo_, z), cO = boff(co, z);
  const long long rO = resv ? boff(ro, z) : 0;
  const int r16 = lane & 15, kg8 = (lane >> 4) * 8;

  f32x4 acc[FM][FN] = {};

  for (int k0 = 0; k0 < K; k0 += 32) {
    // stage A tile [BM][32]
#pragma unroll
    for (int c = tid; c < BM * 4; c += 256) {
      int row = c >> 2, k8 = (c & 3) * 8;
      long long gi = aO + (long long)(bm + row) * ldA + k0 + k8;
      short8 val;
      if constexpr (AMODE == 0) {
        val = *(const short8*)((const short*)Av + gi);
      } else if constexpr (AMODE == 1) {
        short8 x = *(const short8*)((const short*)Av + gi);
        short8 y = *(const short8*)((const short*)A2v + gi);
#pragma unroll
        for (int j = 0; j < 8; ++j) val[j] = f2b(b2f(x[j]) * b2f(y[j]));
      } else if constexpr (AMODE == 2) {
        const float* pf = (const float*)Av + gi;
        float4 f0 = *(const float4*)pf, f1 = *(const float4*)(pf + 4);
        val[0] = f2b(f0.x); val[1] = f2b(f0.y); val[2] = f2b(f0.z); val[3] = f2b(f0.w);
        val[4] = f2b(f1.x); val[5] = f2b(f1.y); val[6] = f2b(f1.z); val[7] = f2b(f1.w);
      } else {  // AMODE == 3: bf16 logits -> exp-normalize on the fly
        short8 x = *(const short8*)((const short*)Av + gi);
        float2 stv = ((const float2*)A2v)[(long long)z * ldRes + bm + row];
#pragma unroll
        for (int j = 0; j < 8; ++j) val[j] = f2b(__expf(b2f(x[j]) - stv.x) * stv.y);
      }
      *(short8*)&As[row][k8] = val;
    }
    // stage B tile [BN][32]
#pragma unroll
    for (int c = tid; c < BN * 4; c += 256) {
      int row = c >> 2, k8 = (c & 3) * 8;
      *(short8*)&Bs[row][k8] =
          *(const short8*)(Bt + bO + (long long)(bn + row) * ldB + k0 + k8);
    }
    __syncthreads();
    short8 af[FM], bfr[FN];
#pragma unroll
    for (int f = 0; f < FM; ++f) af[f] = *(const short8*)&As[wr * WM + f * 16 + r16][kg8];
#pragma unroll
    for (int f = 0; f < FN; ++f) bfr[f] = *(const short8*)&Bs[wc * WN + f * 16 + r16][kg8];
#pragma unroll
    for (int i = 0; i < FM; ++i)
#pragma unroll
      for (int j = 0; j < FN; ++j)
        acc[i][j] = __builtin_amdgcn_mfma_f32_16x16x32_bf16(af[i], bfr[j], acc[i][j], 0, 0, 0);
    __syncthreads();
  }

  // epilogue: D col = lane&15, row = (lane>>4)*4 + r   [m89-verified]
#pragma unroll
  for (int i = 0; i < FM; ++i) {
#pragma unroll
    for (int j = 0; j < FN; ++j) {
      int col = bn + wc * WN + j * 16 + r16;
      float bN = 0.f, eA = 0.f, eB = 0.f;
      if constexpr (PROJ > 0) {
        if (z == 3) bN = biasN[col];
      } else if constexpr (EPI == 1) {
        eA = biasN[col]; eB = biasN[16 + col];
      } else {
        bN = biasN ? biasN[col] : 0.0f;
      }
#pragma unroll
      for (int r = 0; r < 4; ++r) {
        int row = bm + wr * WM + i * 16 + (lane >> 4) * 4 + r;
        if constexpr (PROJ > 0) {
          float v = acc[i][j][r];
          if (z == 3) v = 1.0f / (1.0f + __expf(-(v + bN)));
          long long addr;
          if (z == 2) {
            if constexpr (PROJ == 1)
              addr = 2LL * SRE +
                     (((long long)(row >> 8) * H_ + (col >> 5)) * C_ + (col & 31)) * R_ + (row & 255);
            else
              addr = 2LL * SRE +
                     (((long long)(row & 255) * H_ + (col >> 5)) * C_ + (col & 31)) * S_ + (row >> 8);
          } else {
            addr = (long long)z * SRE + (long long)row * 256 + col;
          }
          ((short*)Cv)[addr] = f2b(v);
        } else {
          float v;
          if constexpr (EPI == 1) {
            float2 st = ((const float2*)A2v)[(long long)z * ldRes + row];
            v = acc[i][j][r] * st.y - st.x * st.y * eA + eB;
          } else {
            v = acc[i][j][r] * scale + bN;
            if (resv) v += resv[rO + (long long)row * ldRes + col];
            if (do_sig) v = 1.0f / (1.0f + __expf(-v));
          }
          long long addr;
          if constexpr (CMODE == 0)
            addr = cO + (long long)row * ldC + col;
          else if constexpr (CMODE == 1)
            addr = (((long long)(row >> 8) * H_ + (col >> 5)) * C_ + (col & 31)) * R_ + (row & 255);
          else if constexpr (CMODE == 2)
            addr = (((long long)(row & 255) * H_ + (col >> 5)) * C_ + (col & 31)) * S_ + (row >> 8);
          else
            addr = (long long)col * (R_ * R_) + row;  // CMODE 3: [h][qk], col<8
          if constexpr (CMODE == 3) {
            if (col < H_) ((float*)Cv)[addr] = v;
          } else if constexpr (OBF) {
            ((short*)Cv)[addr] = f2b(v);
          } else {
            ((float*)Cv)[addr] = v;
          }
        }
      }
    }
  }
}

// ---------------------------------------------------------------- launch
extern "C" void kernel_launch(void* const* d_in, const int* in_sizes, int n_in,
                              void* d_out, int out_size, void* d_ws, size_t ws_size,
                              hipStream_t stream) {
  const float* msa_in    = (const float*)d_in[0];
  const float* pair      = (const float*)d_in[1];
  const float* ln_row_s  = (const float*)d_in[2];
  const float* ln_row_b  = (const float*)d_in[3];
  const float* ln_pair_s = (const float*)d_in[4];
  const float* ln_pair_b = (const float*)d_in[5];
  const float* Wq  = (const float*)d_in[6];
  const float* Wk  = (const float*)d_in[7];
  const float* Wv  = (const float*)d_in[8];
  const float* Wb  = (const float*)d_in[9];
  const float* Wg  = (const float*)d_in[10];
  const float* bg  = (const float*)d_in[11];
  const float* Wo  = (const float*)d_in[12];
  const float* bo  = (const float*)d_in[13];
  const float* ln_col_s = (const float*)d_in[14];
  const float* ln_col_b = (const float*)d_in[15];
  const float* Wq2 = (const float*)d_in[16];
  const float* Wk2 = (const float*)d_in[17];
  const float* Wv2 = (const float*)d_in[18];
  const float* Wg2 = (const float*)d_in[19];
  const float* bg2 = (const float*)d_in[20];
  const float* Wo2 = (const float*)d_in[21];
  const float* bo2 = (const float*)d_in[22];
  const float* W_single = (const float*)d_in[23];
  const float* b_single = (const float*)d_in[24];
  float* out = (float*)d_out;

  // workspace carve; lg is bf16 logits (67 MB full / 16.7 MB chunked)
  float* msa  = (float*)d_ws;                 // 4.19M f32
  short* q_bf = (short*)(msa + SRE);          // q,k,vt,g contiguous SRE-sized (PROJ relies on it)
  short* k_bf = q_bf + SRE;
  short* vt_bf = k_bf + SRE;
  short* g_bf = vt_bf + SRE;
  short* o_bf = g_bf + SRE;
  float* biasb = (float*)(o_bf + SRE);        // [H][R][R] f32 (2.1 MB)
  float2* pbstats = (float2*)(biasb + H_ * R_ * R_);  // pair LN stats (0.5 MB)
  float2* pstats = pbstats + R_ * R_;         // logits row stats [131072] (1 MB)
  short* wp = (short*)(pstats + 131072);      // pair-bias weights [16][128] bf16
  float* AB = (float*)(wp + 16 * 128);        // [32] f32
  short* wT  = (short*)(AB + 32);             // 20 x [256][256] bf16 (B^T)
  short* wsT = wT + 20 * 65536;               // [384][256] bf16
  short* m_bf = wsT + SGL_ * E_;              // LN output (aliases lg head; dead before QK)
  short* lg  = m_bf;                          // bf16 logits

  // ws_size gate: full path needs ~132 MB total; fallback = proven 4-chunk
  const int nch = (ws_size >= (size_t)150 * 1024 * 1024) ? 1 : 4;
  const int zper = 512 / nch;

  hipMemcpyAsync(msa, msa_in, (size_t)SRE * sizeof(float),
                 hipMemcpyDeviceToDevice, stream);
  wt_kernel<<<dim3(16, 1, 20), 256, 0, stream>>>(Wq, Wk, Wv, Wg, Wo,
                                                 Wq2, Wk2, Wv2, Wg2, Wo2, wT);
  wst_kernel<<<24, 256, 0, stream>>>(W_single, wsT);
  pairstats_kernel<<<2048, 256, 0, stream>>>(pair, pbstats);

  const int SR = S_ * R_;
  const BOff Z{0, 0, 0, 0};
  const BOff bW{131072, 0, 0, 0};  // weight-slot stride for PROJ (2 mats of 65536)
  dim3 gproj(2, SR / 128);

  for (int i = 0; i < NB_; ++i) {
    // ================= row attention =================
    ln256_kernel<<<2048, 256, 0, stream>>>(msa, ln_row_s + i * E_, ln_row_b + i * E_, m_bf, SR);
    // fused Q/K/V/G projection: z=0 q, 1 k, 2 v->[S][H][C][R], 3 sigmoid gate
    mgemm<128,128,2,2,0,0,true,0,1><<<dim3(2, SR / 128, 4), 256, 0, stream>>>(
        m_bf, nullptr, wT + i * 65536, bg + (size_t)i * HC_, nullptr, q_bf,
        256, 256, 256, 256, 256, 0, Z, bW, Z, Z, 1.f, 0);
    // pair bias = inv*(pair@(sc.*Wb)) - inv*mu*A + B   (MFMA + algebraic LN)
    pb_prep_kernel<<<1, 128, 0, stream>>>(ln_pair_s + i * P_, ln_pair_b + i * P_,
                                          Wb + (size_t)i * P_ * H_, wp, AB);
    mgemm<128,16,4,1,2,3,false,1><<<dim3(1, 512), 256, 0, stream>>>(
        pair, pbstats, wp, AB, nullptr, biasb,
        16, 128, 128, 128, 0, 0, Z, Z, Z, Z, 1.f, 0);

    for (int c4 = 0; c4 < nch; ++c4) {           // s-chunks (1 chunk when ws allows)
      long long so = (long long)c4 * (zper / 8) * 65536;
      BOff aQ{65536, 3, 7, 32};                  // z=(s_loc,h): (z>>3)*65536+(z&7)*32
      BOff cL{65536, 0, 0, 0};
      BOff rB{0, 0, 7, 65536};                   // bias slice by h
      mgemm<128,128,2,2,0,0,true,0><<<dim3(2, 2, zper), 256, 0, stream>>>(
          q_bf + so, nullptr, k_bf + so, nullptr, biasb, lg,
          256, 32, 256, 256, 256, 256, aQ, aQ, cL, rB, QSCALE, 0);   // bf16 logits out
      rowstats_kernel<4><<<2048, 256, 0, stream>>>(lg, pstats, zper * 256);
      BOff aP{65536, 0, 0, 0}, bV{8192, 0, 0, 0}, cO{65536, 3, 7, 32};
      mgemm<128,32,4,1,3,0,true,0><<<dim3(1, 2, zper), 256, 0, stream>>>(
          lg, pstats, vt_bf + so, nullptr, nullptr, o_bf + so,
          32, 256, 256, 256, 256, 256, aP, bV, cO, Z, 1.f, 0);       // ldRes=256: stats stride
    }
    mgemm<128,128,2,2,1,0,false,0><<<gproj, 256, 0, stream>>>(    // (sig(g).*o)@Wo+bo+msa
        o_bf, g_bf, wT + (8 + i) * 65536, bo + (size_t)i * E_, msa, msa,
        256, 256, 256, 256, 256, 256, Z, Z, Z, Z, 1.f, 0);

    // ================= column attention =================
    ln256_kernel<<<2048, 256, 0, stream>>>(msa, ln_col_s + i * E_, ln_col_b + i * E_, m_bf, SR);
    mgemm<128,128,2,2,0,0,true,0,2><<<dim3(2, SR / 128, 4), 256, 0, stream>>>(
        m_bf, nullptr, wT + (10 + i) * 65536, bg2 + (size_t)i * HC_, nullptr, q_bf,
        256, 256, 256, 256, 256, 0, Z, bW, Z, Z, 1.f, 0);
    {
      BOff aC{256, 3, 7, 32};                    // z=(r,h): (z>>3)*256+(z&7)*32
      BOff cL2{4096, 0, 0, 0};
      mgemm<64,64,2,2,0,0,true,0><<<dim3(1, 1, 2048), 256, 0, stream>>>(
          q_bf, nullptr, k_bf, nullptr, nullptr, lg,
          64, 32, 65536, 65536, 64, 0, aC, aC, cL2, Z, QSCALE, 0);   // bf16 logits out
      rowstats_kernel<1><<<2048, 256, 0, stream>>>(lg, pstats, 131072);
      BOff aP2{4096, 0, 0, 0}, bV2{2048, 0, 0, 0}, cO2{256, 3, 7, 32};
      mgemm<64,32,2,2,3,0,true,0><<<dim3(1, 1, 2048), 256, 0, stream>>>(
          lg, pstats, vt_bf, nullptr, nullptr, o_bf,
          32, 64, 64, 64, 65536, 64, aP2, bV2, cO2, Z, 1.f, 0);      // ldRes=64: stats stride
    }
    mgemm<128,128,2,2,1,0,false,0><<<gproj, 256, 0, stream>>>(
        o_bf, g_bf, wT + (18 + i) * 65536, bo2 + (size_t)i * E_, msa, msa,
        256, 256, 256, 256, 256, 256, Z, Z, Z, Z, 1.f, 0);
  }

  // final: single = msa[0] @ W_single + b_single   [256,384]
  mgemm<128,128,2,2,2,0,false,0><<<dim3(3, 2), 256, 0, stream>>>(
      msa, nullptr, wsT, b_single, nullptr, out,
      384, 256, 256, 256, 384, 0, Z, Z, Z, Z, 1.f, 0);
}